// Round 4
// baseline (98109.827 us; speedup 1.0000x reference)
//
#include <hip/hip_runtime.h>
#include <hip/hip_bf16.h>
#include <cmath>

#define LATENT 6368
#define TSTEPS 64
#define NDATA 16
#define NPANEL 398   /* LATENT/16 */
#define KSPLIT 8
#define NCHUNK 199   /* LATENT/32 */
#define CPS 25       /* ceil(199/8) chunks per slice */
#define NTILE (NPANEL*KSPLIT)   /* 3184 */

#define PBLK 800     /* persistent grid: 796 matvec (x4 waves = 3184 tiles) + MLP block */
#define PMV  796
#define PMLP 799
#define NGRP 16
#define GSIZE (PBLK/NGRP)   /* 50 */

typedef __attribute__((ext_vector_type(8))) short short8v;
typedef __attribute__((ext_vector_type(4))) float floatx4;

__device__ __forceinline__ unsigned short f2bf(float x) {
    union { float f; unsigned u; } c; c.f = x;
    unsigned r = (c.u + 0x7FFFu + ((c.u >> 16) & 1u)) >> 16;
    return (unsigned short)r;
}
__device__ __forceinline__ float bf2f(unsigned short h) {
    union { unsigned u; float f; } c; c.u = ((unsigned)h) << 16; return c.f;
}

// E = A - I split hi/lo bf16. Row-major [LATENT][LATENT].
__global__ __launch_bounds__(256) void convert_E2(const float* __restrict__ A,
                                                  unsigned short* __restrict__ Eh,
                                                  unsigned short* __restrict__ El,
                                                  int total8) {
    int t = blockIdx.x * blockDim.x + threadIdx.x;
    if (t >= total8) return;
    size_t idx = (size_t)t * 8u;
    const float4* src = reinterpret_cast<const float4*>(A + idx);
    float4 v0 = src[0];
    float4 v1 = src[1];
    float v[8] = {v0.x, v0.y, v0.z, v0.w, v1.x, v1.y, v1.z, v1.w};
    unsigned q = (unsigned)(idx % 6369u);
    unsigned jd = (6369u - q) % 6369u;
    if (jd < 8u) v[jd] -= 1.0f;
    union { short8v s; unsigned short u[8]; } oh, ol;
#pragma unroll
    for (int j = 0; j < 8; ++j) {
        unsigned short hb = f2bf(v[j]);
        oh.u[j] = hb;
        ol.u[j] = f2bf(v[j] - bf2f(hb));
    }
    *reinterpret_cast<short8v*>(Eh + idx) = oh.s;
    *reinterpret_cast<short8v*>(El + idx) = ol.s;
}

__global__ __launch_bounds__(256) void init_theta(const float* __restrict__ th0,
                                                  float* __restrict__ T0,
                                                  unsigned short* __restrict__ TT0h,
                                                  unsigned short* __restrict__ TT0l,
                                                  unsigned short* __restrict__ TT1h,
                                                  unsigned short* __restrict__ TT1l) {
    int r = blockIdx.x * blockDim.x + threadIdx.x;
    if (r >= LATENT) return;
    float v = th0[r];
#pragma unroll
    for (int b = 0; b < 8; ++b) T0[r * 8 + b] = v;
    unsigned short hb = f2bf(v);
    unsigned short lb = f2bf(v - bf2f(hb));
#pragma unroll
    for (int n = 0; n < 8; ++n) { TT0h[n * LATENT + r] = hb; TT0l[n * LATENT + r] = lb; }
#pragma unroll
    for (int n = 8; n < 16; ++n) {
        TT0h[n * LATENT + r] = 0; TT0l[n * LATENT + r] = 0;
        TT1h[n * LATENT + r] = 0; TT1l[n * LATENT + r] = 0;
    }
}

// ---------- shared MLP body (used by persistent kernel & fallback combine) ----------
__device__ void run_mlp(const float* __restrict__ Tcur, const float* __restrict__ ts,
                        float* __restrict__ mwrite, float* __restrict__ ys,
                        int i, int tid, float (*h0s)[64], float (*h1s)[64]) {
    int w = tid >> 6;
    int lane = tid & 63;
    for (int it = 0; it < 2; ++it) {
        int b = w * 2 + it;
        float tc = ts[b * TSTEPS + i];
        float tp = (i == 0) ? -ts[b * TSTEPS + 1] : ts[b * TSTEPS + i - 1];
        float rin = 2.f * tc - tp;   // root_in = t + delta_t
        float w0 = Tcur[(size_t)lane * 8 + b];
        float b0 = Tcur[(size_t)(64 + lane) * 8 + b];
        float h0 = fmaxf(w0 * rin + b0, 0.f);
        h0s[b][lane] = h0;
        __syncthreads();
        float h1 = Tcur[(size_t)(4224 + lane) * 8 + b];
#pragma unroll 8
        for (int k = 0; k < 64; ++k)
            h1 += Tcur[(size_t)(128 + lane * 64 + k) * 8 + b] * h0s[b][k];
        h1 = fmaxf(h1, 0.f);
        h1s[b][lane] = h1;
        __syncthreads();
        if (lane < 32) {
            float o = Tcur[(size_t)(6336 + lane) * 8 + b];
#pragma unroll 8
            for (int k = 0; k < 64; ++k)
                o += Tcur[(size_t)(4288 + lane * 64 + k) * 8 + b] * h1s[b][k];
            float z = tanhf(o);
            float res;
            if (lane < 16) { res = z; mwrite[b * NDATA + lane] = z; }
            else           { res = log1pf(expf(z)); }
            ys[(size_t)b * (TSTEPS * 32) + (size_t)i * 32 + lane] = res;
        }
        __syncthreads();
    }
}

// ---------- grid barrier: hierarchical, monotone counters (no reset race) ----------
__device__ __forceinline__ void gsync(unsigned* grpCnt, unsigned* superCnt, unsigned iter) {
    __syncthreads();
    if (threadIdx.x == 0) {
        __threadfence();
        unsigned g = blockIdx.x & (NGRP - 1);
        unsigned v = __hip_atomic_fetch_add(&grpCnt[g * 32], 1u, __ATOMIC_ACQ_REL, __HIP_MEMORY_SCOPE_AGENT);
        if (v == iter * GSIZE - 1u)
            __hip_atomic_fetch_add(superCnt, 1u, __ATOMIC_ACQ_REL, __HIP_MEMORY_SCOPE_AGENT);
        while (__hip_atomic_load(superCnt, __ATOMIC_ACQUIRE, __HIP_MEMORY_SCOPE_AGENT) < iter * NGRP)
            __builtin_amdgcn_s_sleep(4);
        __threadfence();
    }
    __syncthreads();
}

// ---------- persistent cooperative kernel: the whole 64-step scan ----------
__global__ __launch_bounds__(256, 4) void persistent_kernel(
    const unsigned short* __restrict__ Eh, const unsigned short* __restrict__ El,
    float* __restrict__ T0buf, float* __restrict__ T1buf,
    unsigned short* __restrict__ TT0h, unsigned short* __restrict__ TT0l,
    unsigned short* __restrict__ TT1h, unsigned short* __restrict__ TT1l,
    float* __restrict__ mb, float* __restrict__ P,
    const float* __restrict__ Bmat, const float* __restrict__ xs,
    const float* __restrict__ ts, float* __restrict__ ys,
    unsigned* grpCnt, unsigned* superCnt)
{
    __shared__ float ush[17][8];
    __shared__ float h0s[8][64];
    __shared__ float h1s[8][64];
    int tid = threadIdx.x;
    int blk = blockIdx.x;
    int wave = tid >> 6, lane = tid & 63;
    int rowl = lane & 15, kgrp = lane >> 4;
    unsigned iter = 0;
    for (int s = 0; s < TSTEPS; ++s) {
        const float* Tc = (s & 1) ? T1buf : T0buf;
        float* Tn       = (s & 1) ? T0buf : T1buf;
        const unsigned short* THc = (s & 1) ? TT1h : TT0h;
        const unsigned short* TLc = (s & 1) ? TT1l : TT0l;
        unsigned short* THn = (s & 1) ? TT0h : TT1h;
        unsigned short* TLn = (s & 1) ? TT0l : TT1l;
        float* mread  = mb + (s & 1) * 128;
        float* mwrite = mb + ((s & 1) ^ 1) * 128;
        // ---- phase A: matvec partials (one tile per wave) + lagged MLP ----
        if (blk < PMV) {
            int t = blk * 4 + wave;         // 3184 tiles exactly
            int p = t >> 3, si = t & 7;
            int row = p * 16 + rowl;
            int c0 = si * CPS;
            int c1 = c0 + CPS; if (c1 > NCHUNK) c1 = NCHUNK;
            floatx4 acc = {0.f, 0.f, 0.f, 0.f};
            size_t ebase = (size_t)row * LATENT + kgrp * 8;
            size_t tbase = (size_t)rowl * LATENT + kgrp * 8;
            short8v eh = *reinterpret_cast<const short8v*>(Eh + ebase + (size_t)c0 * 32);
            short8v el = *reinterpret_cast<const short8v*>(El + ebase + (size_t)c0 * 32);
            short8v th = *reinterpret_cast<const short8v*>(THc + tbase + (size_t)c0 * 32);
            short8v tl = *reinterpret_cast<const short8v*>(TLc + tbase + (size_t)c0 * 32);
            for (int c = c0; c < c1; ++c) {
                short8v eh2 = eh, el2 = el, th2 = th, tl2 = tl;
                if (c + 1 < c1) {
                    size_t eo = ebase + (size_t)(c + 1) * 32;
                    size_t to = tbase + (size_t)(c + 1) * 32;
                    eh2 = *reinterpret_cast<const short8v*>(Eh + eo);
                    el2 = *reinterpret_cast<const short8v*>(El + eo);
                    th2 = *reinterpret_cast<const short8v*>(THc + to);
                    tl2 = *reinterpret_cast<const short8v*>(TLc + to);
                }
                acc = __builtin_amdgcn_mfma_f32_16x16x32_bf16(eh, th, acc, 0, 0, 0);
                acc = __builtin_amdgcn_mfma_f32_16x16x32_bf16(eh, tl, acc, 0, 0, 0);
                acc = __builtin_amdgcn_mfma_f32_16x16x32_bf16(el, th, acc, 0, 0, 0);
                eh = eh2; el = el2; th = th2; tl = tl2;
            }
            // C/D layout: col = lane&15 (batch), row = kgrp*4 + reg
            if (rowl < 8) {
                int rbase = kgrp * 4;
#pragma unroll
                for (int r = 0; r < 4; ++r)
                    P[(size_t)t * 128 + (rbase + r) * 8 + rowl] = acc[r];
            }
        } else if (blk == PMLP && s >= 1) {
            run_mlp(Tc, ts, mwrite, ys, s - 1, tid, h0s, h1s);
        }
        ++iter; gsync(grpCnt, superCnt, iter);
        // ---- phase B: combine theta_{s+1} (64 outputs per block) ----
        if (blk < PMV) {
            if (tid < 136) {
                int b = tid & 7, j = tid >> 3;
                float tc = ts[b * TSTEPS + s];
                float tp = (s == 0) ? -ts[b * TSTEPS + 1] : ts[b * TSTEPS + s - 1];
                float val;
                if (j == 0) val = tc - tp;
                else {
                    int d = j - 1;
                    float xp = (s < 2) ? xs[(b * TSTEPS) * NDATA + d] : mread[b * NDATA + d];
                    val = xs[(b * TSTEPS + s) * NDATA + d] - xp;
                }
                ush[j][b] = val;
            }
            __syncthreads();
            if (tid < 64) {
                int o = blk * 64 + tid;        // 796*64 = 50944 = LATENT*8
                int r = o >> 3, n = o & 7;
                int pp = r >> 4, mm = r & 15;
                const float* Pb = P + (size_t)(pp * 8) * 128 + mm * 8 + n;
                float sum = 0.f;
#pragma unroll
                for (int si = 0; si < KSPLIT; ++si) sum += Pb[si * 128];
                float val = Tc[r * 8 + n] + sum;
                const float* Brow = Bmat + r * 17;
#pragma unroll
                for (int j = 0; j < 17; ++j) val += Brow[j] * ush[j][n];
                Tn[r * 8 + n] = val;
                unsigned short hb = f2bf(val);
                THn[n * LATENT + r] = hb;
                TLn[n * LATENT + r] = f2bf(val - bf2f(hb));
            }
            __syncthreads();
        }
        ++iter; gsync(grpCnt, superCnt, iter);
    }
    // final MLP: i = 63 uses theta_64 (in T0buf after 64 steps)
    if (blk == PMLP) {
        run_mlp(T0buf, ts, mb, ys, TSTEPS - 1, tid, h0s, h1s);
    }
}

// ---------- fallback path (round-3 structure) ----------
template<bool USE_E>
__global__ __launch_bounds__(128) void partial_kernel(
    const unsigned short* __restrict__ Eh,
    const unsigned short* __restrict__ El,
    const float* __restrict__ Af,
    const unsigned short* __restrict__ TThc,
    const unsigned short* __restrict__ TTlc,
    float* __restrict__ P)
{
    int blk = blockIdx.x;
    int p  = blk >> 3;
    int si = blk & 7;
    int tid = threadIdx.x;
    int wave = tid >> 6;
    int lane = tid & 63;
    int rowl = lane & 15;
    int kgrp = lane >> 4;
    int row = p * 16 + rowl;
    int c0 = si * CPS;
    int c1 = c0 + CPS; if (c1 > NCHUNK) c1 = NCHUNK;
    int nch = c1 - c0;
    int half = (nch + 1) >> 1;
    int cs = c0 + wave * half;
    int ce = cs + half; if (ce > c1) ce = c1;
    floatx4 acc = {0.f, 0.f, 0.f, 0.f};
    for (int c = cs; c < ce; ++c) {
        int k = c * 32 + kgrp * 8;
        size_t eoff = (size_t)row * LATENT + k;
        short8v ehf, elf;
        if (USE_E) {
            ehf = *reinterpret_cast<const short8v*>(Eh + eoff);
            elf = *reinterpret_cast<const short8v*>(El + eoff);
        } else {
            const float* ap = Af + eoff;
            float v[8];
#pragma unroll
            for (int j = 0; j < 8; ++j) v[j] = ap[j];
            int jd = row - k;
            if (jd >= 0 && jd < 8) v[jd] -= 1.0f;
            union { short8v sv; unsigned short us[8]; } ch, cl;
#pragma unroll
            for (int j = 0; j < 8; ++j) {
                unsigned short hb = f2bf(v[j]);
                ch.us[j] = hb;
                cl.us[j] = f2bf(v[j] - bf2f(hb));
            }
            ehf = ch.sv; elf = cl.sv;
        }
        size_t toff = (size_t)rowl * LATENT + k;
        short8v thf = *reinterpret_cast<const short8v*>(TThc + toff);
        short8v tlf = *reinterpret_cast<const short8v*>(TTlc + toff);
        acc = __builtin_amdgcn_mfma_f32_16x16x32_bf16(ehf, thf, acc, 0, 0, 0);
        acc = __builtin_amdgcn_mfma_f32_16x16x32_bf16(ehf, tlf, acc, 0, 0, 0);
        acc = __builtin_amdgcn_mfma_f32_16x16x32_bf16(elf, thf, acc, 0, 0, 0);
    }
    __shared__ float red[2][16][16];
#pragma unroll
    for (int r = 0; r < 4; ++r) red[wave][kgrp * 4 + r][rowl] = acc[r];
    __syncthreads();
    int nn = tid & 15;
    if (nn < 8) {
        for (int mm = tid >> 4; mm < 16; mm += 8) {
            float s2 = red[0][mm][nn] + red[1][mm][nn];
            P[((size_t)(p * 8 + si) * 16 + mm) * 8 + nn] = s2;
        }
    }
}

__global__ __launch_bounds__(256) void combine_kernel(
    const float* __restrict__ P,
    const float* __restrict__ Tcur,
    float* __restrict__ Tnxt,
    unsigned short* __restrict__ TThn,
    unsigned short* __restrict__ TTln,
    const float* __restrict__ Bmat,
    const float* __restrict__ xs,
    const float* __restrict__ ts,
    const float* __restrict__ mread,
    float* __restrict__ mwrite,
    float* __restrict__ ys,
    int s, int do_matvec, int do_mlp)
{
    int tid = threadIdx.x;
    if ((int)blockIdx.x < 199) {
        if (!do_matvec) return;
        __shared__ float u[17][8];
        if (tid < 136) {
            int b = tid & 7;
            int j = tid >> 3;
            float tc = ts[b * TSTEPS + s];
            float tp = (s == 0) ? -ts[b * TSTEPS + 1] : ts[b * TSTEPS + s - 1];
            float val;
            if (j == 0) {
                val = tc - tp;
            } else {
                int d = j - 1;
                float xp = (s < 2) ? xs[(b * TSTEPS) * NDATA + d]
                                   : mread[b * NDATA + d];
                val = xs[(b * TSTEPS + s) * NDATA + d] - xp;
            }
            u[j][b] = val;
        }
        __syncthreads();
        int idx = blockIdx.x * 256 + tid;
        int r = idx >> 3;
        int n = idx & 7;
        int pp = r >> 4, mm = r & 15;
        const float* Pb = P + ((size_t)pp * 8) * 128 + mm * 8 + n;
        float sum = 0.f;
#pragma unroll
        for (int si = 0; si < KSPLIT; ++si) sum += Pb[si * 128];
        float val = Tcur[r * 8 + n] + sum;
        const float* Brow = Bmat + r * 17;
#pragma unroll
        for (int j = 0; j < 17; ++j) val += Brow[j] * u[j][n];
        Tnxt[r * 8 + n] = val;
        unsigned short hb = f2bf(val);
        TThn[n * LATENT + r] = hb;
        TTln[n * LATENT + r] = f2bf(val - bf2f(hb));
    } else {
        if (!do_mlp) return;
        __shared__ float h0s[8][64];
        __shared__ float h1s[8][64];
        run_mlp(Tcur, ts, mwrite, ys, s - 1, tid, h0s, h1s);
    }
}

extern "C" void kernel_launch(void* const* d_in, const int* in_sizes, int n_in,
                              void* d_out, int out_size, void* d_ws, size_t ws_size,
                              hipStream_t stream) {
    const float* xs  = (const float*)d_in[0];
    const float* ts  = (const float*)d_in[1];
    const float* A   = (const float*)d_in[2];
    const float* Bm  = (const float*)d_in[3];
    const float* th0 = (const float*)d_in[4];
    float* ys = (float*)d_out;

    char* ws = (char*)d_ws;
    size_t off = 0;
    auto alloc = [&](size_t bytes) {
        void* p = ws + off;
        off += (bytes + 255) & ~(size_t)255;
        return p;
    };
    float* T0 = (float*)alloc((size_t)LATENT * 8 * sizeof(float));
    float* T1 = (float*)alloc((size_t)LATENT * 8 * sizeof(float));
    unsigned short* TT0h = (unsigned short*)alloc((size_t)16 * LATENT * 2);
    unsigned short* TT0l = (unsigned short*)alloc((size_t)16 * LATENT * 2);
    unsigned short* TT1h = (unsigned short*)alloc((size_t)16 * LATENT * 2);
    unsigned short* TT1l = (unsigned short*)alloc((size_t)16 * LATENT * 2);
    float* mb = (float*)alloc(2 * 8 * 16 * sizeof(float));
    float* P  = (float*)alloc((size_t)NTILE * 128 * sizeof(float));
    unsigned* grpCnt = (unsigned*)alloc(4096);      // [NGRP*32] counters + super
    unsigned* superCnt = grpCnt + NGRP * 32;
    size_t Ebytes = (size_t)LATENT * LATENT * 2;
    bool useE = (off + 2 * Ebytes + 512) <= ws_size;
    unsigned short* EhP = nullptr;
    unsigned short* ElP = nullptr;
    if (useE) {
        EhP = (unsigned short*)alloc(Ebytes);
        ElP = (unsigned short*)alloc(Ebytes);
        int total8 = LATENT * LATENT / 8;
        convert_E2<<<dim3((total8 + 255) / 256), dim3(256), 0, stream>>>(A, EhP, ElP, total8);
    }
    init_theta<<<dim3((LATENT + 255) / 256), dim3(256), 0, stream>>>(th0, T0, TT0h, TT0l, TT1h, TT1l);

    hipError_t coop = hipErrorUnknown;
    if (useE) {
        hipMemsetAsync(grpCnt, 0, 4096, stream);
        void* kargs[] = {
            (void*)&EhP, (void*)&ElP, (void*)&T0, (void*)&T1,
            (void*)&TT0h, (void*)&TT0l, (void*)&TT1h, (void*)&TT1l,
            (void*)&mb, (void*)&P, (void*)&Bm, (void*)&xs, (void*)&ts,
            (void*)&ys, (void*)&grpCnt, (void*)&superCnt };
        coop = hipLaunchCooperativeKernel((void*)persistent_kernel,
                                          dim3(PBLK), dim3(256), kargs, 0, stream);
    }
    if (coop != hipSuccess) {
        // fallback: round-3 multi-launch path
        float* T[2] = {T0, T1};
        unsigned short* TTh[2] = {TT0h, TT1h};
        unsigned short* TTl[2] = {TT0l, TT1l};
        for (int s = 0; s <= TSTEPS; ++s) {
            int cur = s & 1, nxt = cur ^ 1;
            float* mread  = mb + (s & 1) * 128;
            float* mwrite = mb + ((s & 1) ^ 1) * 128;
            int dmv = (s < TSTEPS) ? 1 : 0;
            int dml = (s >= 1) ? 1 : 0;
            if (dmv) {
                if (useE)
                    partial_kernel<true><<<dim3(NTILE), dim3(128), 0, stream>>>(
                        EhP, ElP, A, TTh[cur], TTl[cur], P);
                else
                    partial_kernel<false><<<dim3(NTILE), dim3(128), 0, stream>>>(
                        EhP, ElP, A, TTh[cur], TTl[cur], P);
            }
            combine_kernel<<<dim3(200), dim3(256), 0, stream>>>(
                P, T[cur], T[nxt], TTh[nxt], TTl[nxt],
                Bm, xs, ts, mread, mwrite, ys, s, dmv, dml);
        }
    }
    (void)in_sizes; (void)n_in; (void)out_size;
}

// Round 5
// 7237.559 us; speedup vs baseline: 13.5557x; 13.5557x over previous
//
#include <hip/hip_runtime.h>
#include <hip/hip_bf16.h>
#include <cmath>

#define LATENT 6368
#define TSTEPS 64
#define NDATA 16
#define NPANEL 398   /* LATENT/16 */
#define KSPLIT 8
#define NCHUNK 199   /* LATENT/32 */
#define CPS 25       /* ceil(199/8) chunks per slice */
#define NTILE (NPANEL*KSPLIT)   /* 3184 */

#define PBLK 800     /* persistent grid: 796 matvec (x4 waves = 3184 tiles) + MLP block */
#define PMV  796
#define PMLP 799
#define NGRP 16
#define GSIZE (PBLK/NGRP)   /* 50 */

typedef __attribute__((ext_vector_type(8))) short short8v;
typedef __attribute__((ext_vector_type(4))) float floatx4;

__device__ __forceinline__ unsigned short f2bf(float x) {
    union { float f; unsigned u; } c; c.f = x;
    unsigned r = (c.u + 0x7FFFu + ((c.u >> 16) & 1u)) >> 16;
    return (unsigned short)r;
}
__device__ __forceinline__ float bf2f(unsigned short h) {
    union { unsigned u; float f; } c; c.u = ((unsigned)h) << 16; return c.f;
}

// E = A - I split hi/lo bf16. Row-major [LATENT][LATENT].
__global__ __launch_bounds__(256) void convert_E2(const float* __restrict__ A,
                                                  unsigned short* __restrict__ Eh,
                                                  unsigned short* __restrict__ El,
                                                  int total8) {
    int t = blockIdx.x * blockDim.x + threadIdx.x;
    if (t >= total8) return;
    size_t idx = (size_t)t * 8u;
    const float4* src = reinterpret_cast<const float4*>(A + idx);
    float4 v0 = src[0];
    float4 v1 = src[1];
    float v[8] = {v0.x, v0.y, v0.z, v0.w, v1.x, v1.y, v1.z, v1.w};
    unsigned q = (unsigned)(idx % 6369u);
    unsigned jd = (6369u - q) % 6369u;
    if (jd < 8u) v[jd] -= 1.0f;
    union { short8v s; unsigned short u[8]; } oh, ol;
#pragma unroll
    for (int j = 0; j < 8; ++j) {
        unsigned short hb = f2bf(v[j]);
        oh.u[j] = hb;
        ol.u[j] = f2bf(v[j] - bf2f(hb));
    }
    *reinterpret_cast<short8v*>(Eh + idx) = oh.s;
    *reinterpret_cast<short8v*>(El + idx) = ol.s;
}

__global__ __launch_bounds__(256) void init_theta(const float* __restrict__ th0,
                                                  float* __restrict__ T0,
                                                  unsigned short* __restrict__ TT0h,
                                                  unsigned short* __restrict__ TT0l,
                                                  unsigned short* __restrict__ TT1h,
                                                  unsigned short* __restrict__ TT1l) {
    int r = blockIdx.x * blockDim.x + threadIdx.x;
    if (r >= LATENT) return;
    float v = th0[r];
#pragma unroll
    for (int b = 0; b < 8; ++b) T0[r * 8 + b] = v;
    unsigned short hb = f2bf(v);
    unsigned short lb = f2bf(v - bf2f(hb));
#pragma unroll
    for (int n = 0; n < 8; ++n) { TT0h[n * LATENT + r] = hb; TT0l[n * LATENT + r] = lb; }
#pragma unroll
    for (int n = 8; n < 16; ++n) {
        TT0h[n * LATENT + r] = 0; TT0l[n * LATENT + r] = 0;
        TT1h[n * LATENT + r] = 0; TT1l[n * LATENT + r] = 0;
    }
}

// ---------- shared MLP body ----------
__device__ void run_mlp(const float* __restrict__ Tcur, const float* __restrict__ ts,
                        float* __restrict__ mwrite, float* __restrict__ ys,
                        int i, int tid, float (*h0s)[64], float (*h1s)[64]) {
    int w = tid >> 6;
    int lane = tid & 63;
    for (int it = 0; it < 2; ++it) {
        int b = w * 2 + it;
        float tc = ts[b * TSTEPS + i];
        float tp = (i == 0) ? -ts[b * TSTEPS + 1] : ts[b * TSTEPS + i - 1];
        float rin = 2.f * tc - tp;   // root_in = t + delta_t
        float w0 = Tcur[(size_t)lane * 8 + b];
        float b0 = Tcur[(size_t)(64 + lane) * 8 + b];
        float h0 = fmaxf(w0 * rin + b0, 0.f);
        h0s[b][lane] = h0;
        __syncthreads();
        float h1 = Tcur[(size_t)(4224 + lane) * 8 + b];
#pragma unroll 8
        for (int k = 0; k < 64; ++k)
            h1 += Tcur[(size_t)(128 + lane * 64 + k) * 8 + b] * h0s[b][k];
        h1 = fmaxf(h1, 0.f);
        h1s[b][lane] = h1;
        __syncthreads();
        if (lane < 32) {
            float o = Tcur[(size_t)(6336 + lane) * 8 + b];
#pragma unroll 8
            for (int k = 0; k < 64; ++k)
                o += Tcur[(size_t)(4288 + lane * 64 + k) * 8 + b] * h1s[b][k];
            float z = tanhf(o);
            float res;
            if (lane < 16) { res = z; mwrite[b * NDATA + lane] = z; }
            else           { res = log1pf(expf(z)); }
            ys[(size_t)b * (TSTEPS * 32) + (size_t)i * 32 + lane] = res;
        }
        __syncthreads();
    }
}

// ---------- grid barrier v2: release-arrive, RELAXED poll on write-once epoch,
// ---------- single acquire fence on exit (no per-poll cache invalidation!) ----------
__device__ __forceinline__ void gsync(unsigned* grpCnt, unsigned* superCnt,
                                      unsigned* epoch, unsigned iter) {
    __syncthreads();
    if (threadIdx.x == 0) {
        unsigned g = blockIdx.x & (NGRP - 1);
        // RELEASE: write back this block's dirty L2 lines to the coherence point.
        unsigned v = __hip_atomic_fetch_add(&grpCnt[g * 32], 1u,
                                            __ATOMIC_RELEASE, __HIP_MEMORY_SCOPE_AGENT);
        if (v == iter * GSIZE - 1u) {
            unsigned w = __hip_atomic_fetch_add(superCnt, 1u,
                                                __ATOMIC_RELAXED, __HIP_MEMORY_SCOPE_AGENT);
            if (w == iter * NGRP - 1u)
                __hip_atomic_store(epoch, iter, __ATOMIC_RELAXED, __HIP_MEMORY_SCOPE_AGENT);
        }
        // RELAXED poll: bypasses caches, no invalidation side effects.
        while (__hip_atomic_load(epoch, __ATOMIC_RELAXED, __HIP_MEMORY_SCOPE_AGENT) < iter)
            __builtin_amdgcn_s_sleep(8);
        // One acquire fence: invalidate local caches so phase reads see remote data.
        __builtin_amdgcn_fence(__ATOMIC_ACQUIRE, "agent");
    }
    __syncthreads();
}

// ---------- persistent cooperative kernel: the whole 64-step scan ----------
__global__ __launch_bounds__(256, 4) void persistent_kernel(
    const unsigned short* __restrict__ Eh, const unsigned short* __restrict__ El,
    float* __restrict__ T0buf, float* __restrict__ T1buf,
    unsigned short* __restrict__ TT0h, unsigned short* __restrict__ TT0l,
    unsigned short* __restrict__ TT1h, unsigned short* __restrict__ TT1l,
    float* __restrict__ mb, float* __restrict__ P,
    const float* __restrict__ Bmat, const float* __restrict__ xs,
    const float* __restrict__ ts, float* __restrict__ ys,
    unsigned* grpCnt, unsigned* superCnt, unsigned* epoch)
{
    __shared__ float ush[17][8];
    __shared__ float h0s[8][64];
    __shared__ float h1s[8][64];
    int tid = threadIdx.x;
    int blk = blockIdx.x;
    int wave = tid >> 6, lane = tid & 63;
    int rowl = lane & 15, kgrp = lane >> 4;
    unsigned iter = 0;
    for (int s = 0; s < TSTEPS; ++s) {
        const float* Tc = (s & 1) ? T1buf : T0buf;
        float* Tn       = (s & 1) ? T0buf : T1buf;
        const unsigned short* THc = (s & 1) ? TT1h : TT0h;
        const unsigned short* TLc = (s & 1) ? TT1l : TT0l;
        unsigned short* THn = (s & 1) ? TT0h : TT1h;
        unsigned short* TLn = (s & 1) ? TT0l : TT1l;
        float* mread  = mb + (s & 1) * 128;
        float* mwrite = mb + ((s & 1) ^ 1) * 128;
        // ---- phase A: matvec partials (one tile per wave) + lagged MLP ----
        if (blk < PMV) {
            int t = blk * 4 + wave;         // 3184 tiles exactly
            int p = t >> 3, si = t & 7;
            int row = p * 16 + rowl;
            int c0 = si * CPS;
            int c1 = c0 + CPS; if (c1 > NCHUNK) c1 = NCHUNK;
            floatx4 acc = {0.f, 0.f, 0.f, 0.f};
            size_t ebase = (size_t)row * LATENT + kgrp * 8;
            size_t tbase = (size_t)rowl * LATENT + kgrp * 8;
            short8v eh = *reinterpret_cast<const short8v*>(Eh + ebase + (size_t)c0 * 32);
            short8v el = *reinterpret_cast<const short8v*>(El + ebase + (size_t)c0 * 32);
            short8v th = *reinterpret_cast<const short8v*>(THc + tbase + (size_t)c0 * 32);
            short8v tl = *reinterpret_cast<const short8v*>(TLc + tbase + (size_t)c0 * 32);
            for (int c = c0; c < c1; ++c) {
                short8v eh2 = eh, el2 = el, th2 = th, tl2 = tl;
                if (c + 1 < c1) {
                    size_t eo = ebase + (size_t)(c + 1) * 32;
                    size_t to = tbase + (size_t)(c + 1) * 32;
                    eh2 = *reinterpret_cast<const short8v*>(Eh + eo);
                    el2 = *reinterpret_cast<const short8v*>(El + eo);
                    th2 = *reinterpret_cast<const short8v*>(THc + to);
                    tl2 = *reinterpret_cast<const short8v*>(TLc + to);
                }
                acc = __builtin_amdgcn_mfma_f32_16x16x32_bf16(eh, th, acc, 0, 0, 0);
                acc = __builtin_amdgcn_mfma_f32_16x16x32_bf16(eh, tl, acc, 0, 0, 0);
                acc = __builtin_amdgcn_mfma_f32_16x16x32_bf16(el, th, acc, 0, 0, 0);
                eh = eh2; el = el2; th = th2; tl = tl2;
            }
            // C/D layout: col = lane&15 (batch), row = kgrp*4 + reg
            if (rowl < 8) {
                int rbase = kgrp * 4;
#pragma unroll
                for (int r = 0; r < 4; ++r)
                    P[(size_t)t * 128 + (rbase + r) * 8 + rowl] = acc[r];
            }
        } else if (blk == PMLP && s >= 1) {
            run_mlp(Tc, ts, mwrite, ys, s - 1, tid, h0s, h1s);
        }
        ++iter; gsync(grpCnt, superCnt, epoch, iter);
        // ---- phase B: combine theta_{s+1} (64 outputs per block) ----
        if (blk < PMV) {
            if (tid < 136) {
                int b = tid & 7, j = tid >> 3;
                float tc = ts[b * TSTEPS + s];
                float tp = (s == 0) ? -ts[b * TSTEPS + 1] : ts[b * TSTEPS + s - 1];
                float val;
                if (j == 0) val = tc - tp;
                else {
                    int d = j - 1;
                    float xp = (s < 2) ? xs[(b * TSTEPS) * NDATA + d] : mread[b * NDATA + d];
                    val = xs[(b * TSTEPS + s) * NDATA + d] - xp;
                }
                ush[j][b] = val;
            }
            __syncthreads();
            if (tid < 64) {
                int o = blk * 64 + tid;        // 796*64 = 50944 = LATENT*8
                int r = o >> 3, n = o & 7;
                int pp = r >> 4, mm = r & 15;
                const float* Pb = P + (size_t)(pp * 8) * 128 + mm * 8 + n;
                float sum = 0.f;
#pragma unroll
                for (int si = 0; si < KSPLIT; ++si) sum += Pb[si * 128];
                float val = Tc[r * 8 + n] + sum;
                const float* Brow = Bmat + r * 17;
#pragma unroll
                for (int j = 0; j < 17; ++j) val += Brow[j] * ush[j][n];
                Tn[r * 8 + n] = val;
                unsigned short hb = f2bf(val);
                THn[n * LATENT + r] = hb;
                TLn[n * LATENT + r] = f2bf(val - bf2f(hb));
            }
            __syncthreads();
        }
        ++iter; gsync(grpCnt, superCnt, epoch, iter);
    }
    // final MLP: i = 63 uses theta_64 (in T0buf after 64 steps)
    if (blk == PMLP) {
        run_mlp(T0buf, ts, mb, ys, TSTEPS - 1, tid, h0s, h1s);
    }
}

// ---------- fallback path (round-3 structure) ----------
template<bool USE_E>
__global__ __launch_bounds__(128) void partial_kernel(
    const unsigned short* __restrict__ Eh,
    const unsigned short* __restrict__ El,
    const float* __restrict__ Af,
    const unsigned short* __restrict__ TThc,
    const unsigned short* __restrict__ TTlc,
    float* __restrict__ P)
{
    int blk = blockIdx.x;
    int p  = blk >> 3;
    int si = blk & 7;
    int tid = threadIdx.x;
    int wave = tid >> 6;
    int lane = tid & 63;
    int rowl = lane & 15;
    int kgrp = lane >> 4;
    int row = p * 16 + rowl;
    int c0 = si * CPS;
    int c1 = c0 + CPS; if (c1 > NCHUNK) c1 = NCHUNK;
    int nch = c1 - c0;
    int half = (nch + 1) >> 1;
    int cs = c0 + wave * half;
    int ce = cs + half; if (ce > c1) ce = c1;
    floatx4 acc = {0.f, 0.f, 0.f, 0.f};
    for (int c = cs; c < ce; ++c) {
        int k = c * 32 + kgrp * 8;
        size_t eoff = (size_t)row * LATENT + k;
        short8v ehf, elf;
        if (USE_E) {
            ehf = *reinterpret_cast<const short8v*>(Eh + eoff);
            elf = *reinterpret_cast<const short8v*>(El + eoff);
        } else {
            const float* ap = Af + eoff;
            float v[8];
#pragma unroll
            for (int j = 0; j < 8; ++j) v[j] = ap[j];
            int jd = row - k;
            if (jd >= 0 && jd < 8) v[jd] -= 1.0f;
            union { short8v sv; unsigned short us[8]; } ch, cl;
#pragma unroll
            for (int j = 0; j < 8; ++j) {
                unsigned short hb = f2bf(v[j]);
                ch.us[j] = hb;
                cl.us[j] = f2bf(v[j] - bf2f(hb));
            }
            ehf = ch.sv; elf = cl.sv;
        }
        size_t toff = (size_t)rowl * LATENT + k;
        short8v thf = *reinterpret_cast<const short8v*>(TThc + toff);
        short8v tlf = *reinterpret_cast<const short8v*>(TTlc + toff);
        acc = __builtin_amdgcn_mfma_f32_16x16x32_bf16(ehf, thf, acc, 0, 0, 0);
        acc = __builtin_amdgcn_mfma_f32_16x16x32_bf16(ehf, tlf, acc, 0, 0, 0);
        acc = __builtin_amdgcn_mfma_f32_16x16x32_bf16(elf, thf, acc, 0, 0, 0);
    }
    __shared__ float red[2][16][16];
#pragma unroll
    for (int r = 0; r < 4; ++r) red[wave][kgrp * 4 + r][rowl] = acc[r];
    __syncthreads();
    int nn = tid & 15;
    if (nn < 8) {
        for (int mm = tid >> 4; mm < 16; mm += 8) {
            float s2 = red[0][mm][nn] + red[1][mm][nn];
            P[((size_t)(p * 8 + si) * 16 + mm) * 8 + nn] = s2;
        }
    }
}

__global__ __launch_bounds__(256) void combine_kernel(
    const float* __restrict__ P,
    const float* __restrict__ Tcur,
    float* __restrict__ Tnxt,
    unsigned short* __restrict__ TThn,
    unsigned short* __restrict__ TTln,
    const float* __restrict__ Bmat,
    const float* __restrict__ xs,
    const float* __restrict__ ts,
    const float* __restrict__ mread,
    float* __restrict__ mwrite,
    float* __restrict__ ys,
    int s, int do_matvec, int do_mlp)
{
    int tid = threadIdx.x;
    if ((int)blockIdx.x < 199) {
        if (!do_matvec) return;
        __shared__ float u[17][8];
        if (tid < 136) {
            int b = tid & 7;
            int j = tid >> 3;
            float tc = ts[b * TSTEPS + s];
            float tp = (s == 0) ? -ts[b * TSTEPS + 1] : ts[b * TSTEPS + s - 1];
            float val;
            if (j == 0) {
                val = tc - tp;
            } else {
                int d = j - 1;
                float xp = (s < 2) ? xs[(b * TSTEPS) * NDATA + d]
                                   : mread[b * NDATA + d];
                val = xs[(b * TSTEPS + s) * NDATA + d] - xp;
            }
            u[j][b] = val;
        }
        __syncthreads();
        int idx = blockIdx.x * 256 + tid;
        int r = idx >> 3;
        int n = idx & 7;
        int pp = r >> 4, mm = r & 15;
        const float* Pb = P + ((size_t)pp * 8) * 128 + mm * 8 + n;
        float sum = 0.f;
#pragma unroll
        for (int si = 0; si < KSPLIT; ++si) sum += Pb[si * 128];
        float val = Tcur[r * 8 + n] + sum;
        const float* Brow = Bmat + r * 17;
#pragma unroll
        for (int j = 0; j < 17; ++j) val += Brow[j] * u[j][n];
        Tnxt[r * 8 + n] = val;
        unsigned short hb = f2bf(val);
        TThn[n * LATENT + r] = hb;
        TTln[n * LATENT + r] = f2bf(val - bf2f(hb));
    } else {
        if (!do_mlp) return;
        __shared__ float h0s[8][64];
        __shared__ float h1s[8][64];
        run_mlp(Tcur, ts, mwrite, ys, s - 1, tid, h0s, h1s);
    }
}

extern "C" void kernel_launch(void* const* d_in, const int* in_sizes, int n_in,
                              void* d_out, int out_size, void* d_ws, size_t ws_size,
                              hipStream_t stream) {
    const float* xs  = (const float*)d_in[0];
    const float* ts  = (const float*)d_in[1];
    const float* A   = (const float*)d_in[2];
    const float* Bm  = (const float*)d_in[3];
    const float* th0 = (const float*)d_in[4];
    float* ys = (float*)d_out;

    char* ws = (char*)d_ws;
    size_t off = 0;
    auto alloc = [&](size_t bytes) {
        void* p = ws + off;
        off += (bytes + 255) & ~(size_t)255;
        return p;
    };
    float* T0 = (float*)alloc((size_t)LATENT * 8 * sizeof(float));
    float* T1 = (float*)alloc((size_t)LATENT * 8 * sizeof(float));
    unsigned short* TT0h = (unsigned short*)alloc((size_t)16 * LATENT * 2);
    unsigned short* TT0l = (unsigned short*)alloc((size_t)16 * LATENT * 2);
    unsigned short* TT1h = (unsigned short*)alloc((size_t)16 * LATENT * 2);
    unsigned short* TT1l = (unsigned short*)alloc((size_t)16 * LATENT * 2);
    float* mb = (float*)alloc(2 * 8 * 16 * sizeof(float));
    float* P  = (float*)alloc((size_t)NTILE * 128 * sizeof(float));
    unsigned* grpCnt = (unsigned*)alloc(4096);      // [NGRP*32] group counters
    unsigned* superCnt = grpCnt + NGRP * 32;        // byte offset 2048
    unsigned* epoch    = grpCnt + NGRP * 32 + 64;   // byte offset 2304, own line
    size_t Ebytes = (size_t)LATENT * LATENT * 2;
    bool useE = (off + 2 * Ebytes + 512) <= ws_size;
    unsigned short* EhP = nullptr;
    unsigned short* ElP = nullptr;
    if (useE) {
        EhP = (unsigned short*)alloc(Ebytes);
        ElP = (unsigned short*)alloc(Ebytes);
        int total8 = LATENT * LATENT / 8;
        convert_E2<<<dim3((total8 + 255) / 256), dim3(256), 0, stream>>>(A, EhP, ElP, total8);
    }
    init_theta<<<dim3((LATENT + 255) / 256), dim3(256), 0, stream>>>(th0, T0, TT0h, TT0l, TT1h, TT1l);

    hipError_t coop = hipErrorUnknown;
    if (useE) {
        hipMemsetAsync(grpCnt, 0, 4096, stream);
        void* kargs[] = {
            (void*)&EhP, (void*)&ElP, (void*)&T0, (void*)&T1,
            (void*)&TT0h, (void*)&TT0l, (void*)&TT1h, (void*)&TT1l,
            (void*)&mb, (void*)&P, (void*)&Bm, (void*)&xs, (void*)&ts,
            (void*)&ys, (void*)&grpCnt, (void*)&superCnt, (void*)&epoch };
        coop = hipLaunchCooperativeKernel((void*)persistent_kernel,
                                          dim3(PBLK), dim3(256), kargs, 0, stream);
    }
    if (coop != hipSuccess) {
        // fallback: round-3 multi-launch path
        float* T[2] = {T0, T1};
        unsigned short* TTh[2] = {TT0h, TT1h};
        unsigned short* TTl[2] = {TT0l, TT1l};
        for (int s = 0; s <= TSTEPS; ++s) {
            int cur = s & 1, nxt = cur ^ 1;
            float* mread  = mb + (s & 1) * 128;
            float* mwrite = mb + ((s & 1) ^ 1) * 128;
            int dmv = (s < TSTEPS) ? 1 : 0;
            int dml = (s >= 1) ? 1 : 0;
            if (dmv) {
                if (useE)
                    partial_kernel<true><<<dim3(NTILE), dim3(128), 0, stream>>>(
                        EhP, ElP, A, TTh[cur], TTl[cur], P);
                else
                    partial_kernel<false><<<dim3(NTILE), dim3(128), 0, stream>>>(
                        EhP, ElP, A, TTh[cur], TTl[cur], P);
            }
            combine_kernel<<<dim3(200), dim3(256), 0, stream>>>(
                P, T[cur], T[nxt], TTh[nxt], TTl[nxt],
                Bm, xs, ts, mread, mwrite, ys, s, dmv, dml);
        }
    }
    (void)in_sizes; (void)n_in; (void)out_size;
}

// Round 6
// 3879.173 us; speedup vs baseline: 25.2914x; 1.8657x over previous
//
#include <hip/hip_runtime.h>
#include <hip/hip_bf16.h>
#include <cmath>

#define LATENT 6368
#define TSTEPS 64
#define NDATA 16
#define NPANEL 398   /* LATENT/16 */
#define KSPLIT 8
#define NCHUNK 199   /* LATENT/32 */
#define CPS 25       /* ceil(199/8) chunks per slice (fallback) */
#define NTILE (NPANEL*KSPLIT)

typedef __attribute__((ext_vector_type(8))) short short8v;
typedef __attribute__((ext_vector_type(4))) float floatx4;

__device__ __forceinline__ unsigned short f2bf(float x) {
    union { float f; unsigned u; } c; c.f = x;
    unsigned r = (c.u + 0x7FFFu + ((c.u >> 16) & 1u)) >> 16;
    return (unsigned short)r;
}
__device__ __forceinline__ float bf2f(unsigned short h) {
    union { unsigned u; float f; } c; c.u = ((unsigned)h) << 16; return c.f;
}

// E = A - I split hi/lo bf16. Row-major [LATENT][LATENT].
__global__ __launch_bounds__(256) void convert_E2(const float* __restrict__ A,
                                                  unsigned short* __restrict__ Eh,
                                                  unsigned short* __restrict__ El,
                                                  int total8) {
    int t = blockIdx.x * blockDim.x + threadIdx.x;
    if (t >= total8) return;
    size_t idx = (size_t)t * 8u;
    const float4* src = reinterpret_cast<const float4*>(A + idx);
    float4 v0 = src[0];
    float4 v1 = src[1];
    float v[8] = {v0.x, v0.y, v0.z, v0.w, v1.x, v1.y, v1.z, v1.w};
    unsigned q = (unsigned)(idx % 6369u);
    unsigned jd = (6369u - q) % 6369u;
    if (jd < 8u) v[jd] -= 1.0f;
    union { short8v s; unsigned short u[8]; } oh, ol;
#pragma unroll
    for (int j = 0; j < 8; ++j) {
        unsigned short hb = f2bf(v[j]);
        oh.u[j] = hb;
        ol.u[j] = f2bf(v[j] - bf2f(hb));
    }
    *reinterpret_cast<short8v*>(Eh + idx) = oh.s;
    *reinterpret_cast<short8v*>(El + idx) = ol.s;
}

// Packed theta^T: rows 0..7 = bf16hi(theta[batch]), rows 8..15 = bf16lo.
__global__ __launch_bounds__(256) void init_theta(const float* __restrict__ th0,
                                                  float* __restrict__ T0,
                                                  unsigned short* __restrict__ TTA) {
    int r = blockIdx.x * blockDim.x + threadIdx.x;
    if (r >= LATENT) return;
    float v = th0[r];
#pragma unroll
    for (int b = 0; b < 8; ++b) T0[r * 8 + b] = v;
    unsigned short hb = f2bf(v);
    unsigned short lb = f2bf(v - bf2f(hb));
#pragma unroll
    for (int n = 0; n < 8; ++n) {
        TTA[n * LATENT + r] = hb;
        TTA[(n + 8) * LATENT + r] = lb;
    }
}

// ---------- wave-local MLP for one batch (no LDS, no __syncthreads) ----------
__device__ void mlp_batch(const float* __restrict__ Tcur, const float* __restrict__ ts,
                          float* __restrict__ mwrite, float* __restrict__ ys,
                          int i, int b, int lane) {
    float tc = ts[b * TSTEPS + i];
    float tp = (i == 0) ? -ts[b * TSTEPS + 1] : ts[b * TSTEPS + i - 1];
    float rin = 2.f * tc - tp;   // root_in = t + delta_t
    float h0 = fmaxf(Tcur[(size_t)lane * 8 + b] * rin + Tcur[(size_t)(64 + lane) * 8 + b], 0.f);
    float h1 = Tcur[(size_t)(4224 + lane) * 8 + b];
#pragma unroll 8
    for (int k = 0; k < 64; ++k)
        h1 += Tcur[(size_t)(128 + lane * 64 + k) * 8 + b] * __shfl(h0, k, 64);
    h1 = fmaxf(h1, 0.f);
    float o = 0.f;
    if (lane < 32) o = Tcur[(size_t)(6336 + lane) * 8 + b];
#pragma unroll 8
    for (int k = 0; k < 64; ++k) {
        float hk = __shfl(h1, k, 64);
        if (lane < 32) o += Tcur[(size_t)(4288 + lane * 64 + k) * 8 + b] * hk;
    }
    if (lane < 32) {
        float z = tanhf(o);
        float res;
        if (lane < 16) { res = z; mwrite[b * NDATA + lane] = z; }
        else           { res = log1pf(expf(z)); }  // softplus(tanh)
        ys[(size_t)b * (TSTEPS * 32) + (size_t)i * 32 + lane] = res;
    }
}

// ---------- grid barrier v3: hierarchical, per-group epoch lines ----------
// 399 blocks, 16 groups (g = blk & 15): groups 0..14 have 25 blocks, group 15 has 24.
__device__ __forceinline__ void gsync(unsigned* grpCnt, unsigned* superCnt,
                                      unsigned* gEpoch, unsigned iter) {
    __syncthreads();
    if (threadIdx.x == 0) {
        unsigned g = blockIdx.x & 15u;
        unsigned gsz = (g == 15u) ? 24u : 25u;
        // RELEASE: publish this block's writes (L2 writeback to coherence point).
        unsigned v = __hip_atomic_fetch_add(&grpCnt[g * 32], 1u,
                                            __ATOMIC_RELEASE, __HIP_MEMORY_SCOPE_AGENT);
        if (v == iter * gsz - 1u) {
            unsigned w = __hip_atomic_fetch_add(superCnt, 1u,
                                                __ATOMIC_ACQ_REL, __HIP_MEMORY_SCOPE_AGENT);
            if (w == iter * 16u - 1u) {
#pragma unroll
                for (int i2 = 0; i2 < 16; ++i2)
                    __hip_atomic_store(&gEpoch[i2 * 32], iter, __ATOMIC_RELAXED,
                                       __HIP_MEMORY_SCOPE_AGENT);
            }
        }
        // RELAXED poll on own group's line: <=25 pollers per line.
        while (__hip_atomic_load(&gEpoch[g * 32], __ATOMIC_RELAXED,
                                 __HIP_MEMORY_SCOPE_AGENT) < iter)
            __builtin_amdgcn_s_sleep(16);
        // One acquire fence: invalidate caches so phase reads see remote data.
        __builtin_amdgcn_fence(__ATOMIC_ACQUIRE, "agent");
    }
    __syncthreads();
}

// ---------- persistent cooperative kernel: fused step, 1 barrier/step ----------
__global__ __launch_bounds__(1024, 8) void persistent2(
    const unsigned short* __restrict__ Eh, const unsigned short* __restrict__ El,
    float* __restrict__ T0buf, float* __restrict__ T1buf,
    unsigned short* __restrict__ TTA, unsigned short* __restrict__ TTB,
    float* __restrict__ mb,
    const float* __restrict__ Bmat, const float* __restrict__ xs,
    const float* __restrict__ ts, float* __restrict__ ys,
    unsigned* grpCnt, unsigned* superCnt, unsigned* gEpoch)
{
    __shared__ float red[16][16][16];
    __shared__ float ush[17][8];
    int tid = threadIdx.x, blk = blockIdx.x;
    int wave = tid >> 6, lane = tid & 63;
    int rowl = lane & 15, kgrp = lane >> 4;
    // K-chunk split over 16 waves: waves 0..6 get 13 chunks, 7..15 get 12 (total 199)
    int cs = wave * 12 + (wave < 7 ? wave : 7);
    int ce = cs + (wave < 7 ? 13 : 12);
    unsigned iter = 0;
    for (int s = 0; s < TSTEPS; ++s) {
        const float* Tc = (s & 1) ? T1buf : T0buf;
        float* Tn       = (s & 1) ? T0buf : T1buf;
        const unsigned short* TTc = (s & 1) ? TTB : TTA;
        unsigned short* TTn       = (s & 1) ? TTA : TTB;
        float* mwrite = mb + (s & 1) * 128;
        const float* mread = mb + ((s & 1) ^ 1) * 128;
        if (blk < NPANEL) {
            // u_s into LDS (uses mean_{s-2}, published by last barrier)
            if (tid < 136) {
                int b = tid & 7, j = tid >> 3;
                float tc = ts[b * TSTEPS + s];
                float tp = (s == 0) ? -ts[b * TSTEPS + 1] : ts[b * TSTEPS + s - 1];
                float val;
                if (j == 0) val = tc - tp;
                else {
                    int d = j - 1;
                    float xp = (s < 2) ? xs[(b * TSTEPS) * NDATA + d] : mread[b * NDATA + d];
                    val = xs[(b * TSTEPS + s) * NDATA + d] - xp;
                }
                ush[j][b] = val;
            }
            // full-K matvec for 16 rows, packed theta (hi cols 0-7, lo cols 8-15)
            int row = blk * 16 + rowl;
            floatx4 acc1 = {0.f, 0.f, 0.f, 0.f};
            floatx4 acc2 = {0.f, 0.f, 0.f, 0.f};
            size_t ebase = (size_t)row * LATENT + kgrp * 8;
            size_t tbase = (size_t)rowl * LATENT + kgrp * 8;
            short8v eh = *reinterpret_cast<const short8v*>(Eh + ebase + (size_t)cs * 32);
            short8v el = *reinterpret_cast<const short8v*>(El + ebase + (size_t)cs * 32);
            short8v tp = *reinterpret_cast<const short8v*>(TTc + tbase + (size_t)cs * 32);
            for (int c = cs; c < ce; ++c) {
                short8v eh2 = eh, el2 = el, tp2 = tp;
                if (c + 1 < ce) {
                    size_t eo = ebase + (size_t)(c + 1) * 32;
                    size_t to = tbase + (size_t)(c + 1) * 32;
                    eh2 = *reinterpret_cast<const short8v*>(Eh + eo);
                    el2 = *reinterpret_cast<const short8v*>(El + eo);
                    tp2 = *reinterpret_cast<const short8v*>(TTc + to);
                }
                acc1 = __builtin_amdgcn_mfma_f32_16x16x32_bf16(eh, tp, acc1, 0, 0, 0);
                acc2 = __builtin_amdgcn_mfma_f32_16x16x32_bf16(el, tp, acc2, 0, 0, 0);
                eh = eh2; el = el2; tp = tp2;
            }
            // C/D: col = lane&15, row = kgrp*4 + reg
#pragma unroll
            for (int r = 0; r < 4; ++r)
                red[wave][kgrp * 4 + r][rowl] = acc1[r] + acc2[r];
            __syncthreads();
            if (tid < 128) {
                int m = tid >> 3, n = tid & 7;
                float sum = 0.f;
#pragma unroll
                for (int w = 0; w < 16; ++w) sum += red[w][m][n] + red[w][m][n + 8];
                int r = blk * 16 + m;
                float val = Tc[r * 8 + n] + sum;
                const float* Brow = Bmat + r * 17;
#pragma unroll
                for (int j = 0; j < 17; ++j) val += Brow[j] * ush[j][n];
                Tn[r * 8 + n] = val;
                unsigned short hb = f2bf(val);
                TTn[n * LATENT + r] = hb;
                TTn[(n + 8) * LATENT + r] = f2bf(val - bf2f(hb));
            }
        } else {
            // MLP block: MLP(theta_s) -> ys[s-1], mean_{s-1}
            if (s >= 1 && wave < 8)
                mlp_batch(Tc, ts, mwrite, ys, s - 1, wave, lane);
        }
        ++iter; gsync(grpCnt, superCnt, gEpoch, iter);
    }
    // final MLP: ys[63] from theta_64 (in T0buf after 64 steps)
    if (blk == NPANEL && wave < 8)
        mlp_batch(T0buf, ts, mb, ys, TSTEPS - 1, wave, lane);
}

// ---------- fallback path (multi-launch, packed theta layout) ----------
template<bool USE_E>
__global__ __launch_bounds__(128) void partial_kernel(
    const unsigned short* __restrict__ Eh,
    const unsigned short* __restrict__ El,
    const float* __restrict__ Af,
    const unsigned short* __restrict__ TTc,
    float* __restrict__ P)
{
    int blk = blockIdx.x;
    int p  = blk >> 3;
    int si = blk & 7;
    int tid = threadIdx.x;
    int wave = tid >> 6;
    int lane = tid & 63;
    int rowl = lane & 15;
    int kgrp = lane >> 4;
    int row = p * 16 + rowl;
    int c0 = si * CPS;
    int c1 = c0 + CPS; if (c1 > NCHUNK) c1 = NCHUNK;
    int nch = c1 - c0;
    int half = (nch + 1) >> 1;
    int csw = c0 + wave * half;
    int cew = csw + half; if (cew > c1) cew = c1;
    floatx4 acc1 = {0.f, 0.f, 0.f, 0.f};
    floatx4 acc2 = {0.f, 0.f, 0.f, 0.f};
    for (int c = csw; c < cew; ++c) {
        int k = c * 32 + kgrp * 8;
        size_t eoff = (size_t)row * LATENT + k;
        short8v ehf, elf;
        if (USE_E) {
            ehf = *reinterpret_cast<const short8v*>(Eh + eoff);
            elf = *reinterpret_cast<const short8v*>(El + eoff);
        } else {
            const float* ap = Af + eoff;
            float v[8];
#pragma unroll
            for (int j = 0; j < 8; ++j) v[j] = ap[j];
            int jd = row - k;
            if (jd >= 0 && jd < 8) v[jd] -= 1.0f;
            union { short8v sv; unsigned short us[8]; } ch, cl;
#pragma unroll
            for (int j = 0; j < 8; ++j) {
                unsigned short hb = f2bf(v[j]);
                ch.us[j] = hb;
                cl.us[j] = f2bf(v[j] - bf2f(hb));
            }
            ehf = ch.sv; elf = cl.sv;
        }
        short8v tpf = *reinterpret_cast<const short8v*>(TTc + (size_t)rowl * LATENT + k);
        acc1 = __builtin_amdgcn_mfma_f32_16x16x32_bf16(ehf, tpf, acc1, 0, 0, 0);
        acc2 = __builtin_amdgcn_mfma_f32_16x16x32_bf16(elf, tpf, acc2, 0, 0, 0);
    }
    __shared__ float red[2][16][16];
#pragma unroll
    for (int r = 0; r < 4; ++r) red[wave][kgrp * 4 + r][rowl] = acc1[r] + acc2[r];
    __syncthreads();
    int nn = tid & 15;
    if (nn < 8) {
        for (int mm = tid >> 4; mm < 16; mm += 8) {
            float s2 = red[0][mm][nn] + red[0][mm][nn + 8]
                     + red[1][mm][nn] + red[1][mm][nn + 8];
            P[((size_t)(p * 8 + si) * 16 + mm) * 8 + nn] = s2;
        }
    }
}

__global__ __launch_bounds__(256) void combine_kernel(
    const float* __restrict__ P,
    const float* __restrict__ Tcur,
    float* __restrict__ Tnxt,
    unsigned short* __restrict__ TTn,
    const float* __restrict__ Bmat,
    const float* __restrict__ xs,
    const float* __restrict__ ts,
    const float* __restrict__ mread,
    float* __restrict__ mwrite,
    float* __restrict__ ys,
    int s, int do_matvec, int do_mlp)
{
    int tid = threadIdx.x;
    if ((int)blockIdx.x < 199) {
        if (!do_matvec) return;
        __shared__ float u[17][8];
        if (tid < 136) {
            int b = tid & 7;
            int j = tid >> 3;
            float tc = ts[b * TSTEPS + s];
            float tp = (s == 0) ? -ts[b * TSTEPS + 1] : ts[b * TSTEPS + s - 1];
            float val;
            if (j == 0) val = tc - tp;
            else {
                int d = j - 1;
                float xp = (s < 2) ? xs[(b * TSTEPS) * NDATA + d] : mread[b * NDATA + d];
                val = xs[(b * TSTEPS + s) * NDATA + d] - xp;
            }
            u[j][b] = val;
        }
        __syncthreads();
        int idx = blockIdx.x * 256 + tid;
        int r = idx >> 3;
        int n = idx & 7;
        int pp = r >> 4, mm = r & 15;
        const float* Pb = P + ((size_t)pp * 8) * 128 + mm * 8 + n;
        float sum = 0.f;
#pragma unroll
        for (int si = 0; si < KSPLIT; ++si) sum += Pb[si * 128];
        float val = Tcur[r * 8 + n] + sum;
        const float* Brow = Bmat + r * 17;
#pragma unroll
        for (int j = 0; j < 17; ++j) val += Brow[j] * u[j][n];
        Tnxt[r * 8 + n] = val;
        unsigned short hb = f2bf(val);
        TTn[n * LATENT + r] = hb;
        TTn[(n + 8) * LATENT + r] = f2bf(val - bf2f(hb));
    } else {
        if (!do_mlp) return;
        int w = tid >> 6, lane = tid & 63;
        for (int it = 0; it < 2; ++it)
            mlp_batch(Tcur, ts, mwrite, ys, s - 1, w * 2 + it, lane);
    }
}

extern "C" void kernel_launch(void* const* d_in, const int* in_sizes, int n_in,
                              void* d_out, int out_size, void* d_ws, size_t ws_size,
                              hipStream_t stream) {
    const float* xs  = (const float*)d_in[0];
    const float* ts  = (const float*)d_in[1];
    const float* A   = (const float*)d_in[2];
    const float* Bm  = (const float*)d_in[3];
    const float* th0 = (const float*)d_in[4];
    float* ys = (float*)d_out;

    char* ws = (char*)d_ws;
    size_t off = 0;
    auto alloc = [&](size_t bytes) {
        void* p = ws + off;
        off += (bytes + 255) & ~(size_t)255;
        return p;
    };
    float* T0 = (float*)alloc((size_t)LATENT * 8 * sizeof(float));
    float* T1 = (float*)alloc((size_t)LATENT * 8 * sizeof(float));
    unsigned short* TTA = (unsigned short*)alloc((size_t)16 * LATENT * 2);
    unsigned short* TTB = (unsigned short*)alloc((size_t)16 * LATENT * 2);
    float* mb = (float*)alloc(2 * 8 * 16 * sizeof(float));
    float* P  = (float*)alloc((size_t)NTILE * 128 * sizeof(float));
    unsigned* bar = (unsigned*)alloc(8192);
    unsigned* grpCnt   = bar;             // 16 lines x 128B
    unsigned* superCnt = bar + 512;       // own line
    unsigned* gEpoch   = bar + 544;       // 16 lines x 128B
    size_t Ebytes = (size_t)LATENT * LATENT * 2;
    bool useE = (off + 2 * Ebytes + 512) <= ws_size;
    unsigned short* EhP = nullptr;
    unsigned short* ElP = nullptr;
    if (useE) {
        EhP = (unsigned short*)alloc(Ebytes);
        ElP = (unsigned short*)alloc(Ebytes);
        int total8 = LATENT * LATENT / 8;
        convert_E2<<<dim3((total8 + 255) / 256), dim3(256), 0, stream>>>(A, EhP, ElP, total8);
    }
    init_theta<<<dim3((LATENT + 255) / 256), dim3(256), 0, stream>>>(th0, T0, TTA);

    hipError_t coop = hipErrorUnknown;
    if (useE) {
        hipMemsetAsync(bar, 0, 8192, stream);
        void* kargs[] = {
            (void*)&EhP, (void*)&ElP, (void*)&T0, (void*)&T1,
            (void*)&TTA, (void*)&TTB, (void*)&mb, (void*)&Bm, (void*)&xs,
            (void*)&ts, (void*)&ys, (void*)&grpCnt, (void*)&superCnt, (void*)&gEpoch };
        coop = hipLaunchCooperativeKernel((void*)persistent2,
                                          dim3(NPANEL + 1), dim3(1024), kargs, 0, stream);
    }
    if (coop != hipSuccess) {
        // fallback: multi-launch path (packed theta layout)
        float* T[2] = {T0, T1};
        unsigned short* TT[2] = {TTA, TTB};
        for (int s = 0; s <= TSTEPS; ++s) {
            int cur = s & 1, nxt = cur ^ 1;
            float* mwrite = mb + (s & 1) * 128;
            float* mread  = mb + ((s & 1) ^ 1) * 128;
            int dmv = (s < TSTEPS) ? 1 : 0;
            int dml = (s >= 1) ? 1 : 0;
            if (dmv) {
                if (useE)
                    partial_kernel<true><<<dim3(NTILE), dim3(128), 0, stream>>>(
                        EhP, ElP, A, TT[cur], P);
                else
                    partial_kernel<false><<<dim3(NTILE), dim3(128), 0, stream>>>(
                        EhP, ElP, A, TT[cur], P);
            }
            combine_kernel<<<dim3(200), dim3(256), 0, stream>>>(
                P, T[cur], T[nxt], TT[nxt],
                Bm, xs, ts, mread, mwrite, ys, s, dmv, dml);
        }
    }
    (void)in_sizes; (void)n_in; (void)out_size;
}

// Round 8
// 3808.636 us; speedup vs baseline: 25.7598x; 1.0185x over previous
//
#include <hip/hip_runtime.h>
#include <hip/hip_bf16.h>
#include <cmath>

#define LATENT 6368
#define TSTEPS 64
#define NDATA 16
#define NPANEL 398   /* LATENT/16 */
#define KSPLIT 8
#define NCHUNK 199   /* LATENT/32 */
#define CPS 25       /* ceil(199/8) chunks per slice (fallback) */
#define NTILE (NPANEL*KSPLIT)
#define KBLK 796     /* LATENT/8 */

typedef __attribute__((ext_vector_type(8))) short short8v;
typedef __attribute__((ext_vector_type(4))) float floatx4;

__device__ __forceinline__ unsigned short f2bf(float x) {
    union { float f; unsigned u; } c; c.f = x;
    unsigned r = (c.u + 0x7FFFu + ((c.u >> 16) & 1u)) >> 16;
    return (unsigned short)r;
}
__device__ __forceinline__ float bf2f(unsigned short h) {
    union { unsigned u; float f; } c; c.u = ((unsigned)h) << 16; return c.f;
}

// E = A - I split hi/lo bf16, stored MFMA-fragment-linear:
// Epk[(p*199+c)*1024 + lane*8 + j]       = bf16hi(E[p*16+(lane&15)][c*32+(lane>>4)*8+j])
// Epk[(p*199+c)*1024 + 512 + lane*8 + j] = bf16lo of same.
__global__ __launch_bounds__(256) void convert_E3(const float* __restrict__ A,
                                                  unsigned short* __restrict__ Epk,
                                                  int total) {
    int t = blockIdx.x * 256 + threadIdx.x;    // 0 .. LATENT*KBLK-1
    if (t >= total) return;                    // R7 BUG FIX: LATENT*KBLK % 256 != 0
    int row = t / KBLK;
    int kb  = t - row * KBLK;
    const float4* src = reinterpret_cast<const float4*>(A + (size_t)row * LATENT + kb * 8);
    float4 v0 = src[0];
    float4 v1 = src[1];
    float v[8] = {v0.x, v0.y, v0.z, v0.w, v1.x, v1.y, v1.z, v1.w};
    int jd = row - kb * 8;                     // diagonal element within this 8-chunk
    if (jd >= 0 && jd < 8) v[jd] -= 1.0f;
    union { short8v s; unsigned short u[8]; } oh, ol;
#pragma unroll
    for (int j = 0; j < 8; ++j) {
        unsigned short hb = f2bf(v[j]);
        oh.u[j] = hb;
        ol.u[j] = f2bf(v[j] - bf2f(hb));
    }
    int p = row >> 4, rowl = row & 15, c = kb >> 2, kgrp = kb & 3;
    int lane = kgrp * 16 + rowl;
    size_t base = ((size_t)(p * NCHUNK + c)) * 1024 + lane * 8;
    *reinterpret_cast<short8v*>(Epk + base) = oh.s;
    *reinterpret_cast<short8v*>(Epk + base + 512) = ol.s;
}

// Packed theta^T: rows 0..7 = bf16hi(theta[batch]), rows 8..15 = bf16lo.
__global__ __launch_bounds__(256) void init_theta(const float* __restrict__ th0,
                                                  float* __restrict__ T0,
                                                  unsigned short* __restrict__ TTA) {
    int r = blockIdx.x * blockDim.x + threadIdx.x;
    if (r >= LATENT) return;
    float v = th0[r];
#pragma unroll
    for (int b = 0; b < 8; ++b) T0[r * 8 + b] = v;
    unsigned short hb = f2bf(v);
    unsigned short lb = f2bf(v - bf2f(hb));
#pragma unroll
    for (int n = 0; n < 8; ++n) {
        TTA[n * LATENT + r] = hb;
        TTA[(n + 8) * LATENT + r] = lb;
    }
}

// ---------- wave-local MLP for one batch (no LDS, no __syncthreads) ----------
__device__ void mlp_batch(const float* __restrict__ Tcur, const float* __restrict__ ts,
                          float* __restrict__ mwrite, float* __restrict__ ys,
                          int i, int b, int lane) {
    float tc = ts[b * TSTEPS + i];
    float tp = (i == 0) ? -ts[b * TSTEPS + 1] : ts[b * TSTEPS + i - 1];
    float rin = 2.f * tc - tp;   // root_in = t + delta_t
    float h0 = fmaxf(Tcur[(size_t)lane * 8 + b] * rin + Tcur[(size_t)(64 + lane) * 8 + b], 0.f);
    float h1 = Tcur[(size_t)(4224 + lane) * 8 + b];
#pragma unroll 8
    for (int k = 0; k < 64; ++k)
        h1 += Tcur[(size_t)(128 + lane * 64 + k) * 8 + b] * __shfl(h0, k, 64);
    h1 = fmaxf(h1, 0.f);
    float o = 0.f;
    if (lane < 32) o = Tcur[(size_t)(6336 + lane) * 8 + b];
#pragma unroll 8
    for (int k = 0; k < 64; ++k) {
        float hk = __shfl(h1, k, 64);
        if (lane < 32) o += Tcur[(size_t)(4288 + lane * 64 + k) * 8 + b] * hk;
    }
    if (lane < 32) {
        float z = tanhf(o);
        float res;
        if (lane < 16) { res = z; mwrite[b * NDATA + lane] = z; }
        else           { res = log1pf(expf(z)); }  // softplus(tanh)
        ys[(size_t)b * (TSTEPS * 32) + (size_t)i * 32 + lane] = res;
    }
}

// ---------- grid barrier v3: hierarchical, per-group epoch lines ----------
__device__ __forceinline__ void gsync(unsigned* grpCnt, unsigned* superCnt,
                                      unsigned* gEpoch, unsigned iter) {
    __syncthreads();
    if (threadIdx.x == 0) {
        unsigned g = blockIdx.x & 15u;
        unsigned gsz = (g == 15u) ? 24u : 25u;
        unsigned v = __hip_atomic_fetch_add(&grpCnt[g * 32], 1u,
                                            __ATOMIC_RELEASE, __HIP_MEMORY_SCOPE_AGENT);
        if (v == iter * gsz - 1u) {
            unsigned w = __hip_atomic_fetch_add(superCnt, 1u,
                                                __ATOMIC_ACQ_REL, __HIP_MEMORY_SCOPE_AGENT);
            if (w == iter * 16u - 1u) {
#pragma unroll
                for (int i2 = 0; i2 < 16; ++i2)
                    __hip_atomic_store(&gEpoch[i2 * 32], iter, __ATOMIC_RELAXED,
                                       __HIP_MEMORY_SCOPE_AGENT);
            }
        }
        while (__hip_atomic_load(&gEpoch[g * 32], __ATOMIC_RELAXED,
                                 __HIP_MEMORY_SCOPE_AGENT) < iter)
            __builtin_amdgcn_s_sleep(16);
        __builtin_amdgcn_fence(__ATOMIC_ACQUIRE, "agent");
    }
    __syncthreads();
}

// ---------- persistent cooperative kernel: fused step, 1 barrier/step ----------
__global__ __launch_bounds__(1024, 8) void persistent2(
    const unsigned short* __restrict__ Epk,
    float* __restrict__ T0buf, float* __restrict__ T1buf,
    unsigned short* __restrict__ TTA, unsigned short* __restrict__ TTB,
    float* __restrict__ mb,
    const float* __restrict__ Bmat, const float* __restrict__ xs,
    const float* __restrict__ ts, float* __restrict__ ys,
    unsigned* grpCnt, unsigned* superCnt, unsigned* gEpoch)
{
    __shared__ float red[16][16][16];
    __shared__ float ush[17][8];
    int tid = threadIdx.x, blk = blockIdx.x;
    int wave = tid >> 6, lane = tid & 63;
    int rowl = lane & 15, kgrp = lane >> 4;
    // K-chunk split over 16 waves: waves 0..6 get 13 chunks, 7..15 get 12 (total 199)
    int cs = wave * 12 + (wave < 7 ? wave : 7);
    int ce = cs + (wave < 7 ? 13 : 12);
    unsigned iter = 0;
    for (int s = 0; s < TSTEPS; ++s) {
        const float* Tc = (s & 1) ? T1buf : T0buf;
        float* Tn       = (s & 1) ? T0buf : T1buf;
        const unsigned short* TTc = (s & 1) ? TTB : TTA;
        unsigned short* TTn       = (s & 1) ? TTA : TTB;
        float* mwrite = mb + (s & 1) * 128;
        const float* mread = mb + ((s & 1) ^ 1) * 128;
        if (blk < NPANEL) {
            if (tid < 136) {
                int b = tid & 7, j = tid >> 3;
                float tc = ts[b * TSTEPS + s];
                float tp = (s == 0) ? -ts[b * TSTEPS + 1] : ts[b * TSTEPS + s - 1];
                float val;
                if (j == 0) val = tc - tp;
                else {
                    int d = j - 1;
                    float xp = (s < 2) ? xs[(b * TSTEPS) * NDATA + d] : mread[b * NDATA + d];
                    val = xs[(b * TSTEPS + s) * NDATA + d] - xp;
                }
                ush[j][b] = val;
            }
            // full-K matvec, fragment-linear E, zigzag direction per step
            floatx4 acc1 = {0.f, 0.f, 0.f, 0.f};
            floatx4 acc2 = {0.f, 0.f, 0.f, 0.f};
            int nit = ce - cs;
            int cbeg = (s & 1) ? (ce - 1) : cs;
            long long dE = (s & 1) ? -1024 : 1024;     // shorts per chunk step
            long long dT = (s & 1) ? -32 : 32;
            const unsigned short* ep = Epk + ((size_t)(blk * NCHUNK + cbeg)) * 1024 + lane * 8;
            const unsigned short* tpp = TTc + (size_t)rowl * LATENT + kgrp * 8 + (size_t)cbeg * 32;
            short8v eh = *reinterpret_cast<const short8v*>(ep);
            short8v el = *reinterpret_cast<const short8v*>(ep + 512);
            short8v tp = *reinterpret_cast<const short8v*>(tpp);
            for (int it = 0; it < nit; ++it) {
                short8v eh2 = eh, el2 = el, tp2 = tp;
                if (it + 1 < nit) {
                    const unsigned short* ep2 = ep + dE;
                    const unsigned short* tq2 = tpp + dT;
                    eh2 = *reinterpret_cast<const short8v*>(ep2);
                    el2 = *reinterpret_cast<const short8v*>(ep2 + 512);
                    tp2 = *reinterpret_cast<const short8v*>(tq2);
                }
                acc1 = __builtin_amdgcn_mfma_f32_16x16x32_bf16(eh, tp, acc1, 0, 0, 0);
                acc2 = __builtin_amdgcn_mfma_f32_16x16x32_bf16(el, tp, acc2, 0, 0, 0);
                eh = eh2; el = el2; tp = tp2;
                ep += dE; tpp += dT;
            }
            // C/D: col(lane&15) = batch-slot n, row(kgrp*4+r) = output row m
#pragma unroll
            for (int r = 0; r < 4; ++r)
                red[wave][kgrp * 4 + r][rowl] = acc1[r] + acc2[r];
            __syncthreads();
            if (tid < 128) {
                int m = tid >> 3, n = tid & 7;
                float sum = 0.f;
#pragma unroll
                for (int w = 0; w < 16; ++w) sum += red[w][m][n] + red[w][m][n + 8];
                int r = blk * 16 + m;
                float val = Tc[r * 8 + n] + sum;
                const float* Brow = Bmat + r * 17;
#pragma unroll
                for (int j = 0; j < 17; ++j) val += Brow[j] * ush[j][n];
                Tn[r * 8 + n] = val;
                unsigned short hb = f2bf(val);
                TTn[n * LATENT + r] = hb;
                TTn[(n + 8) * LATENT + r] = f2bf(val - bf2f(hb));
            }
        } else {
            if (s >= 1 && wave < 8)
                mlp_batch(Tc, ts, mwrite, ys, s - 1, wave, lane);
        }
        ++iter; gsync(grpCnt, superCnt, gEpoch, iter);
    }
    if (blk == NPANEL && wave < 8)
        mlp_batch(T0buf, ts, mb, ys, TSTEPS - 1, wave, lane);
}

// ---------- fallback path (multi-launch, fragment-linear E) ----------
template<bool USE_E>
__global__ __launch_bounds__(128) void partial_kernel(
    const unsigned short* __restrict__ Epk,
    const float* __restrict__ Af,
    const unsigned short* __restrict__ TTc,
    float* __restrict__ P)
{
    int blk = blockIdx.x;
    int p  = blk >> 3;
    int si = blk & 7;
    int tid = threadIdx.x;
    int wave = tid >> 6;
    int lane = tid & 63;
    int rowl = lane & 15;
    int kgrp = lane >> 4;
    int row = p * 16 + rowl;
    int c0 = si * CPS;
    int c1 = c0 + CPS; if (c1 > NCHUNK) c1 = NCHUNK;
    int nch = c1 - c0;
    int half = (nch + 1) >> 1;
    int csw = c0 + wave * half;
    int cew = csw + half; if (cew > c1) cew = c1;
    floatx4 acc1 = {0.f, 0.f, 0.f, 0.f};
    floatx4 acc2 = {0.f, 0.f, 0.f, 0.f};
    for (int c = csw; c < cew; ++c) {
        int k = c * 32 + kgrp * 8;
        short8v ehf, elf;
        if (USE_E) {
            const unsigned short* ep = Epk + ((size_t)(p * NCHUNK + c)) * 1024 + lane * 8;
            ehf = *reinterpret_cast<const short8v*>(ep);
            elf = *reinterpret_cast<const short8v*>(ep + 512);
        } else {
            const float* ap = Af + (size_t)row * LATENT + k;
            float v[8];
#pragma unroll
            for (int j = 0; j < 8; ++j) v[j] = ap[j];
            int jd = row - k;
            if (jd >= 0 && jd < 8) v[jd] -= 1.0f;
            union { short8v sv; unsigned short us[8]; } ch, cl;
#pragma unroll
            for (int j = 0; j < 8; ++j) {
                unsigned short hb = f2bf(v[j]);
                ch.us[j] = hb;
                cl.us[j] = f2bf(v[j] - bf2f(hb));
            }
            ehf = ch.sv; elf = cl.sv;
        }
        short8v tpf = *reinterpret_cast<const short8v*>(TTc + (size_t)rowl * LATENT + k);
        acc1 = __builtin_amdgcn_mfma_f32_16x16x32_bf16(ehf, tpf, acc1, 0, 0, 0);
        acc2 = __builtin_amdgcn_mfma_f32_16x16x32_bf16(elf, tpf, acc2, 0, 0, 0);
    }
    __shared__ float red[2][16][16];
#pragma unroll
    for (int r = 0; r < 4; ++r) red[wave][kgrp * 4 + r][rowl] = acc1[r] + acc2[r];
    __syncthreads();
    int nn = tid & 15;
    if (nn < 8) {
        for (int mm = tid >> 4; mm < 16; mm += 8) {
            float s2 = red[0][mm][nn] + red[0][mm][nn + 8]
                     + red[1][mm][nn] + red[1][mm][nn + 8];
            P[((size_t)(p * 8 + si) * 16 + mm) * 8 + nn] = s2;
        }
    }
}

__global__ __launch_bounds__(256) void combine_kernel(
    const float* __restrict__ P,
    const float* __restrict__ Tcur,
    float* __restrict__ Tnxt,
    unsigned short* __restrict__ TTn,
    const float* __restrict__ Bmat,
    const float* __restrict__ xs,
    const float* __restrict__ ts,
    const float* __restrict__ mread,
    float* __restrict__ mwrite,
    float* __restrict__ ys,
    int s, int do_matvec, int do_mlp)
{
    int tid = threadIdx.x;
    if ((int)blockIdx.x < 199) {
        if (!do_matvec) return;
        __shared__ float u[17][8];
        if (tid < 136) {
            int b = tid & 7;
            int j = tid >> 3;
            float tc = ts[b * TSTEPS + s];
            float tp = (s == 0) ? -ts[b * TSTEPS + 1] : ts[b * TSTEPS + s - 1];
            float val;
            if (j == 0) val = tc - tp;
            else {
                int d = j - 1;
                float xp = (s < 2) ? xs[(b * TSTEPS) * NDATA + d] : mread[b * NDATA + d];
                val = xs[(b * TSTEPS + s) * NDATA + d] - xp;
            }
            u[j][b] = val;
        }
        __syncthreads();
        int idx = blockIdx.x * 256 + tid;
        int r = idx >> 3;
        int n = idx & 7;
        int pp = r >> 4, mm = r & 15;
        const float* Pb = P + ((size_t)pp * 8) * 128 + mm * 8 + n;
        float sum = 0.f;
#pragma unroll
        for (int si = 0; si < KSPLIT; ++si) sum += Pb[si * 128];
        float val = Tcur[r * 8 + n] + sum;
        const float* Brow = Bmat + r * 17;
#pragma unroll
        for (int j = 0; j < 17; ++j) val += Brow[j] * u[j][n];
        Tnxt[r * 8 + n] = val;
        unsigned short hb = f2bf(val);
        TTn[n * LATENT + r] = hb;
        TTn[(n + 8) * LATENT + r] = f2bf(val - bf2f(hb));
    } else {
        if (!do_mlp) return;
        int w = tid >> 6, lane = tid & 63;
        for (int it = 0; it < 2; ++it)
            mlp_batch(Tcur, ts, mwrite, ys, s - 1, w * 2 + it, lane);
    }
}

extern "C" void kernel_launch(void* const* d_in, const int* in_sizes, int n_in,
                              void* d_out, int out_size, void* d_ws, size_t ws_size,
                              hipStream_t stream) {
    const float* xs  = (const float*)d_in[0];
    const float* ts  = (const float*)d_in[1];
    const float* A   = (const float*)d_in[2];
    const float* Bm  = (const float*)d_in[3];
    const float* th0 = (const float*)d_in[4];
    float* ys = (float*)d_out;

    char* ws = (char*)d_ws;
    size_t off = 0;
    auto alloc = [&](size_t bytes) {
        void* p = ws + off;
        off += (bytes + 255) & ~(size_t)255;
        return p;
    };
    float* T0 = (float*)alloc((size_t)LATENT * 8 * sizeof(float));
    float* T1 = (float*)alloc((size_t)LATENT * 8 * sizeof(float));
    unsigned short* TTA = (unsigned short*)alloc((size_t)16 * LATENT * 2);
    unsigned short* TTB = (unsigned short*)alloc((size_t)16 * LATENT * 2);
    float* mb = (float*)alloc(2 * 8 * 16 * sizeof(float));
    float* P  = (float*)alloc((size_t)NTILE * 128 * sizeof(float));
    unsigned* bar = (unsigned*)alloc(8192);
    unsigned* grpCnt   = bar;             // 16 lines x 128B
    unsigned* superCnt = bar + 512;       // own line
    unsigned* gEpoch   = bar + 544;       // 16 lines x 128B
    size_t Ebytes = (size_t)NPANEL * NCHUNK * 1024 * 2;   // fragment-linear hi+lo
    bool useE = (off + Ebytes + 512) <= ws_size;
    unsigned short* Epk = nullptr;
    if (useE) {
        Epk = (unsigned short*)alloc(Ebytes);
        int nthr = LATENT * KBLK;   // NOT divisible by 256 — ceil + guard (R7 bug)
        convert_E3<<<dim3((nthr + 255) / 256), dim3(256), 0, stream>>>(A, Epk, nthr);
    }
    init_theta<<<dim3((LATENT + 255) / 256), dim3(256), 0, stream>>>(th0, T0, TTA);

    hipError_t coop = hipErrorUnknown;
    if (useE) {
        hipMemsetAsync(bar, 0, 8192, stream);
        void* kargs[] = {
            (void*)&Epk, (void*)&T0, (void*)&T1,
            (void*)&TTA, (void*)&TTB, (void*)&mb, (void*)&Bm, (void*)&xs,
            (void*)&ts, (void*)&ys, (void*)&grpCnt, (void*)&superCnt, (void*)&gEpoch };
        coop = hipLaunchCooperativeKernel((void*)persistent2,
                                          dim3(NPANEL + 1), dim3(1024), kargs, 0, stream);
    }
    if (coop != hipSuccess) {
        // fallback: multi-launch path (fragment-linear E layout)
        float* T[2] = {T0, T1};
        unsigned short* TT[2] = {TTA, TTB};
        for (int s = 0; s <= TSTEPS; ++s) {
            int cur = s & 1, nxt = cur ^ 1;
            float* mwrite = mb + (s & 1) * 128;
            float* mread  = mb + ((s & 1) ^ 1) * 128;
            int dmv = (s < TSTEPS) ? 1 : 0;
            int dml = (s >= 1) ? 1 : 0;
            if (dmv) {
                if (useE)
                    partial_kernel<true><<<dim3(NTILE), dim3(128), 0, stream>>>(
                        Epk, A, TT[cur], P);
                else
                    partial_kernel<false><<<dim3(NTILE), dim3(128), 0, stream>>>(
                        Epk, A, TT[cur], P);
            }
            combine_kernel<<<dim3(200), dim3(256), 0, stream>>>(
                P, T[cur], T[nxt], TT[nxt],
                Bm, xs, ts, mread, mwrite, ys, s, dmv, dml);
        }
    }
    (void)in_sizes; (void)n_in; (void)out_size;
}

// Round 9
// 3537.793 us; speedup vs baseline: 27.7319x; 1.0766x over previous
//
#include <hip/hip_runtime.h>
#include <hip/hip_bf16.h>
#include <cmath>

#define LATENT 6368
#define TSTEPS 64
#define NDATA 16
#define NPANEL 398   /* LATENT/16 */
#define KSPLIT 8
#define NCHUNK 199   /* LATENT/32 */
#define CPS 25       /* ceil(199/8) (fallback) */
#define NTILE (NPANEL*KSPLIT)
#define KBLK 796     /* LATENT/8 */

typedef __attribute__((ext_vector_type(8))) short short8v;
typedef __attribute__((ext_vector_type(4))) float floatx4;

__device__ __forceinline__ unsigned short f2bf(float x) {
    union { float f; unsigned u; } c; c.f = x;
    unsigned r = (c.u + 0x7FFFu + ((c.u >> 16) & 1u)) >> 16;
    return (unsigned short)r;
}
__device__ __forceinline__ float bf2f(unsigned short h) {
    union { unsigned u; float f; } c; c.u = ((unsigned)h) << 16; return c.f;
}

// ---------- pass 1: per-row scale S[r] = max|E_row|/32767 ----------
__global__ __launch_bounds__(64) void row_scale(const float* __restrict__ A,
                                                float* __restrict__ S) {
    int row = blockIdx.x;
    int lane = threadIdx.x;
    const float* Ar = A + (size_t)row * LATENT;
    float m = 0.f;
    for (int i = 0; i < 25; ++i) {
        int idx = i * 256 + lane * 4;
        if (idx + 4 <= LATENT) {
            float4 v = *reinterpret_cast<const float4*>(Ar + idx);
            float a0 = v.x - (idx + 0 == row ? 1.f : 0.f);
            float a1 = v.y - (idx + 1 == row ? 1.f : 0.f);
            float a2 = v.z - (idx + 2 == row ? 1.f : 0.f);
            float a3 = v.w - (idx + 3 == row ? 1.f : 0.f);
            m = fmaxf(m, fmaxf(fmaxf(fabsf(a0), fabsf(a1)), fmaxf(fabsf(a2), fabsf(a3))));
        }
    }
#pragma unroll
    for (int o = 32; o; o >>= 1) m = fmaxf(m, __shfl_xor(m, o, 64));
    if (lane == 0) S[row] = fmaxf(m, 1e-30f) * (1.0f / 32767.0f);
}

// ---------- pass 2: quantize E to int16, fragment-linear ----------
// Eq[(p*199+c)*512 + lane*8 + j] = rint(E[p*16+(lane&15)][c*32+(lane>>4)*8+j] / S[row])
__global__ __launch_bounds__(256) void convert_Eq(const float* __restrict__ A,
                                                  const float* __restrict__ S,
                                                  short* __restrict__ Eq,
                                                  int total) {
    int t = blockIdx.x * 256 + threadIdx.x;
    if (t >= total) return;                    // LATENT*KBLK % 256 != 0 (R7 lesson)
    int row = t / KBLK;
    int kb  = t - row * KBLK;
    const float4* src = reinterpret_cast<const float4*>(A + (size_t)row * LATENT + kb * 8);
    float4 v0 = src[0];
    float4 v1 = src[1];
    float v[8] = {v0.x, v0.y, v0.z, v0.w, v1.x, v1.y, v1.z, v1.w};
    int jd = row - kb * 8;
    if (jd >= 0 && jd < 8) v[jd] -= 1.0f;
    float inv = 1.0f / S[row];                 // = 32767/rowmax (rcp rounding harmless)
    union { short8v s; short q[8]; } o;
#pragma unroll
    for (int j = 0; j < 8; ++j) {
        float qf = rintf(v[j] * inv);
        qf = fminf(fmaxf(qf, -32767.f), 32767.f);
        o.q[j] = (short)qf;
    }
    int p = row >> 4, rowl = row & 15, c = kb >> 2, kgrp = kb & 3;
    int lane = kgrp * 16 + rowl;
    *reinterpret_cast<short8v*>(Eq + ((size_t)(p * NCHUNK + c)) * 512 + lane * 8) = o.s;
}

// Packed theta^T: rows 0..7 = bf16hi(theta[batch]), rows 8..15 = bf16lo.
__global__ __launch_bounds__(256) void init_theta(const float* __restrict__ th0,
                                                  float* __restrict__ T0,
                                                  unsigned short* __restrict__ TTA) {
    int r = blockIdx.x * blockDim.x + threadIdx.x;
    if (r >= LATENT) return;
    float v = th0[r];
#pragma unroll
    for (int b = 0; b < 8; ++b) T0[r * 8 + b] = v;
    unsigned short hb = f2bf(v);
    unsigned short lb = f2bf(v - bf2f(hb));
#pragma unroll
    for (int n = 0; n < 8; ++n) {
        TTA[n * LATENT + r] = hb;
        TTA[(n + 8) * LATENT + r] = lb;
    }
}

// ---------- wave-local MLP for one batch ----------
__device__ void mlp_batch(const float* __restrict__ Tcur, const float* __restrict__ ts,
                          float* __restrict__ mwrite, float* __restrict__ ys,
                          int i, int b, int lane) {
    float tc = ts[b * TSTEPS + i];
    float tp = (i == 0) ? -ts[b * TSTEPS + 1] : ts[b * TSTEPS + i - 1];
    float rin = 2.f * tc - tp;   // root_in = t + delta_t
    float h0 = fmaxf(Tcur[(size_t)lane * 8 + b] * rin + Tcur[(size_t)(64 + lane) * 8 + b], 0.f);
    float h1 = Tcur[(size_t)(4224 + lane) * 8 + b];
#pragma unroll 8
    for (int k = 0; k < 64; ++k)
        h1 += Tcur[(size_t)(128 + lane * 64 + k) * 8 + b] * __shfl(h0, k, 64);
    h1 = fmaxf(h1, 0.f);
    float o = 0.f;
    if (lane < 32) o = Tcur[(size_t)(6336 + lane) * 8 + b];
#pragma unroll 8
    for (int k = 0; k < 64; ++k) {
        float hk = __shfl(h1, k, 64);
        if (lane < 32) o += Tcur[(size_t)(4288 + lane * 64 + k) * 8 + b] * hk;
    }
    if (lane < 32) {
        float z = tanhf(o);
        float res;
        if (lane < 16) { res = z; mwrite[b * NDATA + lane] = z; }
        else           { res = log1pf(expf(z)); }  // softplus(tanh)
        ys[(size_t)b * (TSTEPS * 32) + (size_t)i * 32 + lane] = res;
    }
}

// ---------- grid barrier v3: hierarchical, per-group epoch lines ----------
__device__ __forceinline__ void gsync(unsigned* grpCnt, unsigned* superCnt,
                                      unsigned* gEpoch, unsigned iter) {
    __syncthreads();
    if (threadIdx.x == 0) {
        unsigned g = blockIdx.x & 15u;
        unsigned gsz = (g == 15u) ? 24u : 25u;
        unsigned v = __hip_atomic_fetch_add(&grpCnt[g * 32], 1u,
                                            __ATOMIC_RELEASE, __HIP_MEMORY_SCOPE_AGENT);
        if (v == iter * gsz - 1u) {
            unsigned w = __hip_atomic_fetch_add(superCnt, 1u,
                                                __ATOMIC_ACQ_REL, __HIP_MEMORY_SCOPE_AGENT);
            if (w == iter * 16u - 1u) {
#pragma unroll
                for (int i2 = 0; i2 < 16; ++i2)
                    __hip_atomic_store(&gEpoch[i2 * 32], iter, __ATOMIC_RELAXED,
                                       __HIP_MEMORY_SCOPE_AGENT);
            }
        }
        while (__hip_atomic_load(&gEpoch[g * 32], __ATOMIC_RELAXED,
                                 __HIP_MEMORY_SCOPE_AGENT) < iter)
            __builtin_amdgcn_s_sleep(16);
        __builtin_amdgcn_fence(__ATOMIC_ACQUIRE, "agent");
    }
    __syncthreads();
}

// ---------- persistent cooperative kernel: int16-E fused step ----------
__global__ __launch_bounds__(1024, 8) void persistent3(
    const short* __restrict__ Eq, const float* __restrict__ S,
    float* __restrict__ T0buf, float* __restrict__ T1buf,
    unsigned short* __restrict__ TTA, unsigned short* __restrict__ TTB,
    float* __restrict__ mb,
    const float* __restrict__ Bmat, const float* __restrict__ xs,
    const float* __restrict__ ts, float* __restrict__ ys,
    unsigned* grpCnt, unsigned* superCnt, unsigned* gEpoch)
{
    __shared__ float red[16][16][16];
    __shared__ float ush[17][8];
    int tid = threadIdx.x, blk = blockIdx.x;
    int wave = tid >> 6, lane = tid & 63;
    int rowl = lane & 15, kgrp = lane >> 4;
    // K-chunk split over 16 waves: waves 0..6 get 13 chunks, 7..15 get 12 (total 199)
    int cs = wave * 12 + (wave < 7 ? wave : 7);
    int ce = cs + (wave < 7 ? 13 : 12);
    unsigned iter = 0;
    for (int s = 0; s < TSTEPS; ++s) {
        const float* Tc = (s & 1) ? T1buf : T0buf;
        float* Tn       = (s & 1) ? T0buf : T1buf;
        const unsigned short* TTc = (s & 1) ? TTB : TTA;
        unsigned short* TTn       = (s & 1) ? TTA : TTB;
        float* mwrite = mb + (s & 1) * 128;
        const float* mread = mb + ((s & 1) ^ 1) * 128;
        if (blk < NPANEL) {
            if (tid < 136) {
                int b = tid & 7, j = tid >> 3;
                float tc = ts[b * TSTEPS + s];
                float tp = (s == 0) ? -ts[b * TSTEPS + 1] : ts[b * TSTEPS + s - 1];
                float val;
                if (j == 0) val = tc - tp;
                else {
                    int d = j - 1;
                    float xp = (s < 2) ? xs[(b * TSTEPS) * NDATA + d] : mread[b * NDATA + d];
                    val = xs[(b * TSTEPS + s) * NDATA + d] - xp;
                }
                ush[j][b] = val;
            }
            // full-K matvec, int16 fragment-linear E, zigzag per step
            floatx4 acc1 = {0.f, 0.f, 0.f, 0.f};
            floatx4 acc2 = {0.f, 0.f, 0.f, 0.f};
            int nit = ce - cs;
            int cbeg = (s & 1) ? (ce - 1) : cs;
            long long dE = (s & 1) ? -512 : 512;       // shorts per chunk step
            long long dT = (s & 1) ? -32 : 32;
            const short* ep = Eq + ((size_t)(blk * NCHUNK + cbeg)) * 512 + lane * 8;
            const unsigned short* tpp = TTc + (size_t)rowl * LATENT + kgrp * 8 + (size_t)cbeg * 32;
            short8v ev = *reinterpret_cast<const short8v*>(ep);
            short8v tp = *reinterpret_cast<const short8v*>(tpp);
            for (int it = 0; it < nit; ++it) {
                short8v ev2 = ev, tp2 = tp;
                if (it + 1 < nit) {
                    ev2 = *reinterpret_cast<const short8v*>(ep + dE);
                    tp2 = *reinterpret_cast<const short8v*>(tpp + dT);
                }
                // exact expansion: int16 -> bf16 hi + bf16 lo
                union { short8v sv; unsigned short us[8]; } EH, EL;
#pragma unroll
                for (int j = 0; j < 8; ++j) {
                    float vf = (float)(int)ev[j];          // exact
                    unsigned short hb = f2bf(vf);
                    EH.us[j] = hb;
                    EL.us[j] = f2bf(vf - bf2f(hb));        // exact residual
                }
                acc1 = __builtin_amdgcn_mfma_f32_16x16x32_bf16(EH.sv, tp, acc1, 0, 0, 0);
                acc2 = __builtin_amdgcn_mfma_f32_16x16x32_bf16(EL.sv, tp, acc2, 0, 0, 0);
                ev = ev2; tp = tp2;
                ep += dE; tpp += dT;
            }
            // C/D: col(lane&15) = batch-slot, row(kgrp*4+r) = output row
#pragma unroll
            for (int r = 0; r < 4; ++r)
                red[wave][kgrp * 4 + r][rowl] = acc1[r] + acc2[r];
            __syncthreads();
            if (tid < 128) {
                int m = tid >> 3, n = tid & 7;
                float sum = 0.f;
#pragma unroll
                for (int w = 0; w < 16; ++w) sum += red[w][m][n] + red[w][m][n + 8];
                int r = blk * 16 + m;
                float val = Tc[r * 8 + n] + S[r] * sum;    // apply row scale HERE
                const float* Brow = Bmat + r * 17;
#pragma unroll
                for (int j = 0; j < 17; ++j) val += Brow[j] * ush[j][n];
                Tn[r * 8 + n] = val;
                unsigned short hb = f2bf(val);
                TTn[n * LATENT + r] = hb;
                TTn[(n + 8) * LATENT + r] = f2bf(val - bf2f(hb));
            }
        } else {
            if (s >= 1 && wave < 8)
                mlp_batch(Tc, ts, mwrite, ys, s - 1, wave, lane);
        }
        ++iter; gsync(grpCnt, superCnt, gEpoch, iter);
    }
    if (blk == NPANEL && wave < 8)
        mlp_batch(T0buf, ts, mb, ys, TSTEPS - 1, wave, lane);
}

// ---------- fallback path (multi-launch, int16 E) ----------
template<bool USE_E>
__global__ __launch_bounds__(128) void partial_kernel(
    const short* __restrict__ Eq, const float* __restrict__ S,
    const float* __restrict__ Af,
    const unsigned short* __restrict__ TTc,
    float* __restrict__ P)
{
    int blk = blockIdx.x;
    int p  = blk >> 3;
    int si = blk & 7;
    int tid = threadIdx.x;
    int wave = tid >> 6;
    int lane = tid & 63;
    int rowl = lane & 15;
    int kgrp = lane >> 4;
    int row = p * 16 + rowl;
    int c0 = si * CPS;
    int c1 = c0 + CPS; if (c1 > NCHUNK) c1 = NCHUNK;
    int nch = c1 - c0;
    int half = (nch + 1) >> 1;
    int csw = c0 + wave * half;
    int cew = csw + half; if (cew > c1) cew = c1;
    floatx4 acc1 = {0.f, 0.f, 0.f, 0.f};
    floatx4 acc2 = {0.f, 0.f, 0.f, 0.f};
    for (int c = csw; c < cew; ++c) {
        int k = c * 32 + kgrp * 8;
        short8v ehf, elf;
        if (USE_E) {
            short8v ev = *reinterpret_cast<const short8v*>(
                Eq + ((size_t)(p * NCHUNK + c)) * 512 + lane * 8);
            union { short8v sv; unsigned short us[8]; } EH, EL;
#pragma unroll
            for (int j = 0; j < 8; ++j) {
                float vf = (float)(int)ev[j];
                unsigned short hb = f2bf(vf);
                EH.us[j] = hb;
                EL.us[j] = f2bf(vf - bf2f(hb));
            }
            ehf = EH.sv; elf = EL.sv;
        } else {
            const float* ap = Af + (size_t)row * LATENT + k;
            float v[8];
#pragma unroll
            for (int j = 0; j < 8; ++j) v[j] = ap[j];
            int jd = row - k;
            if (jd >= 0 && jd < 8) v[jd] -= 1.0f;
            union { short8v sv; unsigned short us[8]; } ch, cl;
#pragma unroll
            for (int j = 0; j < 8; ++j) {
                unsigned short hb = f2bf(v[j]);
                ch.us[j] = hb;
                cl.us[j] = f2bf(v[j] - bf2f(hb));
            }
            ehf = ch.sv; elf = cl.sv;
        }
        short8v tpf = *reinterpret_cast<const short8v*>(TTc + (size_t)rowl * LATENT + k);
        acc1 = __builtin_amdgcn_mfma_f32_16x16x32_bf16(ehf, tpf, acc1, 0, 0, 0);
        acc2 = __builtin_amdgcn_mfma_f32_16x16x32_bf16(elf, tpf, acc2, 0, 0, 0);
    }
    __shared__ float red[2][16][16];
#pragma unroll
    for (int r = 0; r < 4; ++r) red[wave][kgrp * 4 + r][rowl] = acc1[r] + acc2[r];
    __syncthreads();
    int nn = tid & 15;
    if (nn < 8) {
        for (int mm = tid >> 4; mm < 16; mm += 8) {
            float s2 = red[0][mm][nn] + red[0][mm][nn + 8]
                     + red[1][mm][nn] + red[1][mm][nn + 8];
            if (USE_E) s2 *= S[p * 16 + mm];
            P[((size_t)(p * 8 + si) * 16 + mm) * 8 + nn] = s2;
        }
    }
}

__global__ __launch_bounds__(256) void combine_kernel(
    const float* __restrict__ P,
    const float* __restrict__ Tcur,
    float* __restrict__ Tnxt,
    unsigned short* __restrict__ TTn,
    const float* __restrict__ Bmat,
    const float* __restrict__ xs,
    const float* __restrict__ ts,
    const float* __restrict__ mread,
    float* __restrict__ mwrite,
    float* __restrict__ ys,
    int s, int do_matvec, int do_mlp)
{
    int tid = threadIdx.x;
    if ((int)blockIdx.x < 199) {
        if (!do_matvec) return;
        __shared__ float u[17][8];
        if (tid < 136) {
            int b = tid & 7;
            int j = tid >> 3;
            float tc = ts[b * TSTEPS + s];
            float tp = (s == 0) ? -ts[b * TSTEPS + 1] : ts[b * TSTEPS + s - 1];
            float val;
            if (j == 0) val = tc - tp;
            else {
                int d = j - 1;
                float xp = (s < 2) ? xs[(b * TSTEPS) * NDATA + d] : mread[b * NDATA + d];
                val = xs[(b * TSTEPS + s) * NDATA + d] - xp;
            }
            u[j][b] = val;
        }
        __syncthreads();
        int idx = blockIdx.x * 256 + tid;
        int r = idx >> 3;
        int n = idx & 7;
        int pp = r >> 4, mm = r & 15;
        const float* Pb = P + ((size_t)pp * 8) * 128 + mm * 8 + n;
        float sum = 0.f;
#pragma unroll
        for (int si = 0; si < KSPLIT; ++si) sum += Pb[si * 128];
        float val = Tcur[r * 8 + n] + sum;
        const float* Brow = Bmat + r * 17;
#pragma unroll
        for (int j = 0; j < 17; ++j) val += Brow[j] * u[j][n];
        Tnxt[r * 8 + n] = val;
        unsigned short hb = f2bf(val);
        TTn[n * LATENT + r] = hb;
        TTn[(n + 8) * LATENT + r] = f2bf(val - bf2f(hb));
    } else {
        if (!do_mlp) return;
        int w = tid >> 6, lane = tid & 63;
        for (int it = 0; it < 2; ++it)
            mlp_batch(Tcur, ts, mwrite, ys, s - 1, w * 2 + it, lane);
    }
}

extern "C" void kernel_launch(void* const* d_in, const int* in_sizes, int n_in,
                              void* d_out, int out_size, void* d_ws, size_t ws_size,
                              hipStream_t stream) {
    const float* xs  = (const float*)d_in[0];
    const float* ts  = (const float*)d_in[1];
    const float* A   = (const float*)d_in[2];
    const float* Bm  = (const float*)d_in[3];
    const float* th0 = (const float*)d_in[4];
    float* ys = (float*)d_out;

    char* ws = (char*)d_ws;
    size_t off = 0;
    auto alloc = [&](size_t bytes) {
        void* p = ws + off;
        off += (bytes + 255) & ~(size_t)255;
        return p;
    };
    float* T0 = (float*)alloc((size_t)LATENT * 8 * sizeof(float));
    float* T1 = (float*)alloc((size_t)LATENT * 8 * sizeof(float));
    unsigned short* TTA = (unsigned short*)alloc((size_t)16 * LATENT * 2);
    unsigned short* TTB = (unsigned short*)alloc((size_t)16 * LATENT * 2);
    float* mb = (float*)alloc(2 * 8 * 16 * sizeof(float));
    float* P  = (float*)alloc((size_t)NTILE * 128 * sizeof(float));
    float* S  = (float*)alloc((size_t)LATENT * sizeof(float));
    unsigned* bar = (unsigned*)alloc(8192);
    unsigned* grpCnt   = bar;             // 16 lines x 128B
    unsigned* superCnt = bar + 512;       // own line
    unsigned* gEpoch   = bar + 544;       // 16 lines x 128B
    size_t Ebytes = (size_t)NPANEL * NCHUNK * 512 * 2;   // int16 fragment-linear: 81 MB
    bool useE = (off + Ebytes + 512) <= ws_size;
    short* Eq = nullptr;
    if (useE) {
        Eq = (short*)alloc(Ebytes);
        row_scale<<<dim3(LATENT), dim3(64), 0, stream>>>(A, S);
        int nthr = LATENT * KBLK;         // NOT divisible by 256: ceil + guard
        convert_Eq<<<dim3((nthr + 255) / 256), dim3(256), 0, stream>>>(A, S, Eq, nthr);
    }
    init_theta<<<dim3((LATENT + 255) / 256), dim3(256), 0, stream>>>(th0, T0, TTA);

    hipError_t coop = hipErrorUnknown;
    if (useE) {
        hipMemsetAsync(bar, 0, 8192, stream);
        void* kargs[] = {
            (void*)&Eq, (void*)&S, (void*)&T0, (void*)&T1,
            (void*)&TTA, (void*)&TTB, (void*)&mb, (void*)&Bm, (void*)&xs,
            (void*)&ts, (void*)&ys, (void*)&grpCnt, (void*)&superCnt, (void*)&gEpoch };
        coop = hipLaunchCooperativeKernel((void*)persistent3,
                                          dim3(NPANEL + 1), dim3(1024), kargs, 0, stream);
    }
    if (coop != hipSuccess) {
        // fallback: multi-launch path
        float* T[2] = {T0, T1};
        unsigned short* TT[2] = {TTA, TTB};
        for (int s = 0; s <= TSTEPS; ++s) {
            int cur = s & 1, nxt = cur ^ 1;
            float* mwrite = mb + (s & 1) * 128;
            float* mread  = mb + ((s & 1) ^ 1) * 128;
            int dmv = (s < TSTEPS) ? 1 : 0;
            int dml = (s >= 1) ? 1 : 0;
            if (dmv) {
                if (useE)
                    partial_kernel<true><<<dim3(NTILE), dim3(128), 0, stream>>>(
                        Eq, S, A, TT[cur], P);
                else
                    partial_kernel<false><<<dim3(NTILE), dim3(128), 0, stream>>>(
                        Eq, S, A, TT[cur], P);
            }
            combine_kernel<<<dim3(200), dim3(256), 0, stream>>>(
                P, T[cur], T[nxt], TT[nxt],
                Bm, xs, ts, mread, mwrite, ys, s, dmv, dml);
        }
    }
    (void)in_sizes; (void)n_in; (void)out_size;
}

// Round 10
// 3218.844 us; speedup vs baseline: 30.4798x; 1.0991x over previous
//
#include <hip/hip_runtime.h>
#include <hip/hip_bf16.h>
#include <cmath>

#define LATENT 6368
#define TSTEPS 64
#define NDATA 16
#define NPANEL 398   /* LATENT/16 */
#define KSPLIT 8
#define NCHUNK 199   /* LATENT/32 */
#define CPS 25       /* ceil(199/8) (fallback) */
#define NTILE (NPANEL*KSPLIT)
#define KBLK 796     /* LATENT/8 */

typedef __attribute__((ext_vector_type(8))) short short8v;
typedef __attribute__((ext_vector_type(4))) float floatx4;

__device__ __forceinline__ unsigned short f2bf(float x) {
    union { float f; unsigned u; } c; c.f = x;
    unsigned r = (c.u + 0x7FFFu + ((c.u >> 16) & 1u)) >> 16;
    return (unsigned short)r;
}
__device__ __forceinline__ float bf2f(unsigned short h) {
    union { unsigned u; float f; } c; c.u = ((unsigned)h) << 16; return c.f;
}

// ---------- pass 1: per-row scale S[r] = max|E_row|/32767 ----------
__global__ __launch_bounds__(64) void row_scale(const float* __restrict__ A,
                                                float* __restrict__ S) {
    int row = blockIdx.x;
    int lane = threadIdx.x;
    const float* Ar = A + (size_t)row * LATENT;
    float m = 0.f;
    for (int i = 0; i < 25; ++i) {
        int idx = i * 256 + lane * 4;
        if (idx + 4 <= LATENT) {
            float4 v = *reinterpret_cast<const float4*>(Ar + idx);
            float a0 = v.x - (idx + 0 == row ? 1.f : 0.f);
            float a1 = v.y - (idx + 1 == row ? 1.f : 0.f);
            float a2 = v.z - (idx + 2 == row ? 1.f : 0.f);
            float a3 = v.w - (idx + 3 == row ? 1.f : 0.f);
            m = fmaxf(m, fmaxf(fmaxf(fabsf(a0), fabsf(a1)), fmaxf(fabsf(a2), fabsf(a3))));
        }
    }
#pragma unroll
    for (int o = 32; o; o >>= 1) m = fmaxf(m, __shfl_xor(m, o, 64));
    if (lane == 0) S[row] = fmaxf(m, 1e-30f) * (1.0f / 32767.0f);
}

// ---------- pass 2: quantize E to int16, fragment-linear ----------
__global__ __launch_bounds__(256) void convert_Eq(const float* __restrict__ A,
                                                  const float* __restrict__ S,
                                                  short* __restrict__ Eq,
                                                  int total) {
    int t = blockIdx.x * 256 + threadIdx.x;
    if (t >= total) return;                    // LATENT*KBLK % 256 != 0 (R7 lesson)
    int row = t / KBLK;
    int kb  = t - row * KBLK;
    const float4* src = reinterpret_cast<const float4*>(A + (size_t)row * LATENT + kb * 8);
    float4 v0 = src[0];
    float4 v1 = src[1];
    float v[8] = {v0.x, v0.y, v0.z, v0.w, v1.x, v1.y, v1.z, v1.w};
    int jd = row - kb * 8;
    if (jd >= 0 && jd < 8) v[jd] -= 1.0f;
    float inv = 1.0f / S[row];
    union { short8v s; short q[8]; } o;
#pragma unroll
    for (int j = 0; j < 8; ++j) {
        float qf = rintf(v[j] * inv);
        qf = fminf(fmaxf(qf, -32767.f), 32767.f);
        o.q[j] = (short)qf;
    }
    int p = row >> 4, rowl = row & 15, c = kb >> 2, kgrp = kb & 3;
    int lane = kgrp * 16 + rowl;
    *reinterpret_cast<short8v*>(Eq + ((size_t)(p * NCHUNK + c)) * 512 + lane * 8) = o.s;
}

// Packed theta^T: rows 0..7 = bf16hi(theta[batch]), rows 8..15 = bf16lo.
__global__ __launch_bounds__(256) void init_theta(const float* __restrict__ th0,
                                                  float* __restrict__ T0,
                                                  unsigned short* __restrict__ TTA) {
    int r = blockIdx.x * blockDim.x + threadIdx.x;
    if (r >= LATENT) return;
    float v = th0[r];
#pragma unroll
    for (int b = 0; b < 8; ++b) T0[r * 8 + b] = v;
    unsigned short hb = f2bf(v);
    unsigned short lb = f2bf(v - bf2f(hb));
#pragma unroll
    for (int n = 0; n < 8; ++n) {
        TTA[n * LATENT + r] = hb;
        TTA[(n + 8) * LATENT + r] = lb;
    }
}

// ---------- wave-local MLP for one batch ----------
__device__ void mlp_batch(const float* __restrict__ Tcur, const float* __restrict__ ts,
                          float* __restrict__ mwrite, float* __restrict__ ys,
                          int i, int b, int lane) {
    float tc = ts[b * TSTEPS + i];
    float tp = (i == 0) ? -ts[b * TSTEPS + 1] : ts[b * TSTEPS + i - 1];
    float rin = 2.f * tc - tp;   // root_in = t + delta_t
    float h0 = fmaxf(Tcur[(size_t)lane * 8 + b] * rin + Tcur[(size_t)(64 + lane) * 8 + b], 0.f);
    float h1 = Tcur[(size_t)(4224 + lane) * 8 + b];
#pragma unroll 8
    for (int k = 0; k < 64; ++k)
        h1 += Tcur[(size_t)(128 + lane * 64 + k) * 8 + b] * __shfl(h0, k, 64);
    h1 = fmaxf(h1, 0.f);
    float o = 0.f;
    if (lane < 32) o = Tcur[(size_t)(6336 + lane) * 8 + b];
#pragma unroll 8
    for (int k = 0; k < 64; ++k) {
        float hk = __shfl(h1, k, 64);
        if (lane < 32) o += Tcur[(size_t)(4288 + lane * 64 + k) * 8 + b] * hk;
    }
    if (lane < 32) {
        float z = tanhf(o);
        float res;
        if (lane < 16) { res = z; mwrite[b * NDATA + lane] = z; }
        else           { res = log1pf(expf(z)); }  // softplus(tanh)
        ys[(size_t)b * (TSTEPS * 32) + (size_t)i * 32 + lane] = res;
    }
}

// ---------- grid barrier v3: hierarchical, per-group epoch lines ----------
__device__ __forceinline__ void gsync(unsigned* grpCnt, unsigned* superCnt,
                                      unsigned* gEpoch, unsigned iter) {
    __syncthreads();
    if (threadIdx.x == 0) {
        unsigned g = blockIdx.x & 15u;
        unsigned gsz = (g == 15u) ? 24u : 25u;
        unsigned v = __hip_atomic_fetch_add(&grpCnt[g * 32], 1u,
                                            __ATOMIC_RELEASE, __HIP_MEMORY_SCOPE_AGENT);
        if (v == iter * gsz - 1u) {
            unsigned w = __hip_atomic_fetch_add(superCnt, 1u,
                                                __ATOMIC_ACQ_REL, __HIP_MEMORY_SCOPE_AGENT);
            if (w == iter * 16u - 1u) {
#pragma unroll
                for (int i2 = 0; i2 < 16; ++i2)
                    __hip_atomic_store(&gEpoch[i2 * 32], iter, __ATOMIC_RELAXED,
                                       __HIP_MEMORY_SCOPE_AGENT);
            }
        }
        while (__hip_atomic_load(&gEpoch[g * 32], __ATOMIC_RELAXED,
                                 __HIP_MEMORY_SCOPE_AGENT) < iter)
            __builtin_amdgcn_s_sleep(16);
        __builtin_amdgcn_fence(__ATOMIC_ACQUIRE, "agent");
    }
    __syncthreads();
}

// exact int16 -> bf16(hi8)*256 + bf16(lo8) expansion + 2 MFMAs (no rounding ops:
// hi8 in [-128,127], lo8 in [0,255] are exactly representable in bf16, so f32->bf16
// truncation (>>16) is exact).
#define COMP(EV, TP) do {                                                       \
    union { short8v sv; unsigned short us[8]; } EHu, ELu;                       \
    _Pragma("unroll")                                                           \
    for (int j = 0; j < 8; ++j) {                                               \
        int q = (EV)[j];                                                        \
        union { float f; unsigned u; } ch, cl;                                  \
        ch.f = (float)(q >> 8);                                                 \
        cl.f = (float)(q & 255);                                                \
        EHu.us[j] = (unsigned short)(ch.u >> 16);                               \
        ELu.us[j] = (unsigned short)(cl.u >> 16);                               \
    }                                                                           \
    acc1 = __builtin_amdgcn_mfma_f32_16x16x32_bf16(EHu.sv, (TP), acc1, 0, 0, 0);\
    acc2 = __builtin_amdgcn_mfma_f32_16x16x32_bf16(ELu.sv, (TP), acc2, 0, 0, 0);\
} while (0)

#define LDE(P)  (*reinterpret_cast<const short8v*>(P))

// ---------- persistent cooperative kernel: depth-4 pipelined int16-E step ----------
__global__ __launch_bounds__(512, 4) void persistent4(
    const short* __restrict__ Eq, const float* __restrict__ S,
    float* __restrict__ T0buf, float* __restrict__ T1buf,
    unsigned short* __restrict__ TTA, unsigned short* __restrict__ TTB,
    float* __restrict__ mb,
    const float* __restrict__ Bmat, const float* __restrict__ xs,
    const float* __restrict__ ts, float* __restrict__ ys,
    unsigned* grpCnt, unsigned* superCnt, unsigned* gEpoch)
{
    __shared__ float red[8][16][16];
    __shared__ float ush[17][8];
    int tid = threadIdx.x, blk = blockIdx.x;
    int wave = tid >> 6, lane = tid & 63;
    int rowl = lane & 15, kgrp = lane >> 4;
    // K-chunk split over 8 waves: waves 0..6 get 25 chunks, wave 7 gets 24 (total 199)
    int cs = (wave < 7) ? wave * 25 : 175;
    int ce = cs + ((wave < 7) ? 25 : 24);
    unsigned iter = 0;
    for (int s = 0; s < TSTEPS; ++s) {
        const float* Tc = (s & 1) ? T1buf : T0buf;
        float* Tn       = (s & 1) ? T0buf : T1buf;
        const unsigned short* TTc = (s & 1) ? TTB : TTA;
        unsigned short* TTn       = (s & 1) ? TTA : TTB;
        float* mwrite = mb + (s & 1) * 128;
        const float* mread = mb + ((s & 1) ^ 1) * 128;
        if (blk < NPANEL) {
            if (tid < 136) {
                int b = tid & 7, j = tid >> 3;
                float tc = ts[b * TSTEPS + s];
                float tp = (s == 0) ? -ts[b * TSTEPS + 1] : ts[b * TSTEPS + s - 1];
                float val;
                if (j == 0) val = tc - tp;
                else {
                    int d = j - 1;
                    float xp = (s < 2) ? xs[(b * TSTEPS) * NDATA + d] : mread[b * NDATA + d];
                    val = xs[(b * TSTEPS + s) * NDATA + d] - xp;
                }
                ush[j][b] = val;
            }
            // full-K matvec, depth-4 software pipeline (static register rotation)
            floatx4 acc1 = {0.f, 0.f, 0.f, 0.f};
            floatx4 acc2 = {0.f, 0.f, 0.f, 0.f};
            const short* ep = Eq + ((size_t)(blk * NCHUNK + cs)) * 512 + lane * 8;
            const unsigned short* tq = TTc + (size_t)rowl * LATENT + kgrp * 8 + (size_t)cs * 32;
            short8v e0 = LDE(ep),        e1 = LDE(ep + 512),
                    e2 = LDE(ep + 1024), e3 = LDE(ep + 1536);
            short8v t0 = LDE(tq),        t1 = LDE(tq + 32),
                    t2 = LDE(tq + 64),   t3 = LDE(tq + 96);
            int c = cs;
            for (; c + 8 <= ce; c += 4) {
                COMP(e0, t0); e0 = LDE(ep + 2048); t0 = LDE(tq + 128);
                COMP(e1, t1); e1 = LDE(ep + 2560); t1 = LDE(tq + 160);
                COMP(e2, t2); e2 = LDE(ep + 3072); t2 = LDE(tq + 192);
                COMP(e3, t3); e3 = LDE(ep + 3584); t3 = LDE(tq + 224);
                ep += 2048; tq += 128;
            }
            COMP(e0, t0); COMP(e1, t1); COMP(e2, t2); COMP(e3, t3);
            for (int k2 = 4; c + k2 < ce; ++k2) {
                e0 = LDE(ep + k2 * 512); t0 = LDE(tq + k2 * 32);
                COMP(e0, t0);
            }
            // C/D: col(lane&15) = batch-slot, row(kgrp*4+r) = output row
#pragma unroll
            for (int r = 0; r < 4; ++r)
                red[wave][kgrp * 4 + r][rowl] = 256.f * acc1[r] + acc2[r];
            __syncthreads();
            if (tid < 128) {
                int m = tid >> 3, n = tid & 7;
                float sum = 0.f;
#pragma unroll
                for (int w = 0; w < 8; ++w) sum += red[w][m][n] + red[w][m][n + 8];
                int r = blk * 16 + m;
                float val = Tc[r * 8 + n] + S[r] * sum;
                const float* Brow = Bmat + r * 17;
#pragma unroll
                for (int j = 0; j < 17; ++j) val += Brow[j] * ush[j][n];
                Tn[r * 8 + n] = val;
                unsigned short hb = f2bf(val);
                TTn[n * LATENT + r] = hb;
                TTn[(n + 8) * LATENT + r] = f2bf(val - bf2f(hb));
            }
        } else {
            if (s >= 1)
                mlp_batch(Tc, ts, mwrite, ys, s - 1, wave, lane);
        }
        ++iter; gsync(grpCnt, superCnt, gEpoch, iter);
    }
    if (blk == NPANEL)
        mlp_batch(T0buf, ts, mb, ys, TSTEPS - 1, wave, lane);
}

// ---------- fallback path (multi-launch, int16 E) ----------
template<bool USE_E>
__global__ __launch_bounds__(128) void partial_kernel(
    const short* __restrict__ Eq, const float* __restrict__ S,
    const float* __restrict__ Af,
    const unsigned short* __restrict__ TTc,
    float* __restrict__ P)
{
    int blk = blockIdx.x;
    int p  = blk >> 3;
    int si = blk & 7;
    int tid = threadIdx.x;
    int wave = tid >> 6;
    int lane = tid & 63;
    int rowl = lane & 15;
    int kgrp = lane >> 4;
    int row = p * 16 + rowl;
    int c0 = si * CPS;
    int c1 = c0 + CPS; if (c1 > NCHUNK) c1 = NCHUNK;
    int nch = c1 - c0;
    int half = (nch + 1) >> 1;
    int csw = c0 + wave * half;
    int cew = csw + half; if (cew > c1) cew = c1;
    floatx4 acc1 = {0.f, 0.f, 0.f, 0.f};
    floatx4 acc2 = {0.f, 0.f, 0.f, 0.f};
    for (int c = csw; c < cew; ++c) {
        int k = c * 32 + kgrp * 8;
        short8v ehf, elf;
        if (USE_E) {
            short8v ev = *reinterpret_cast<const short8v*>(
                Eq + ((size_t)(p * NCHUNK + c)) * 512 + lane * 8);
            union { short8v sv; unsigned short us[8]; } EH, EL;
#pragma unroll
            for (int j = 0; j < 8; ++j) {
                float vf = (float)(int)ev[j];
                unsigned short hb = f2bf(vf);
                EH.us[j] = hb;
                EL.us[j] = f2bf(vf - bf2f(hb));
            }
            ehf = EH.sv; elf = EL.sv;
        } else {
            const float* ap = Af + (size_t)row * LATENT + k;
            float v[8];
#pragma unroll
            for (int j = 0; j < 8; ++j) v[j] = ap[j];
            int jd = row - k;
            if (jd >= 0 && jd < 8) v[jd] -= 1.0f;
            union { short8v sv; unsigned short us[8]; } ch, cl;
#pragma unroll
            for (int j = 0; j < 8; ++j) {
                unsigned short hb = f2bf(v[j]);
                ch.us[j] = hb;
                cl.us[j] = f2bf(v[j] - bf2f(hb));
            }
            ehf = ch.sv; elf = cl.sv;
        }
        short8v tpf = *reinterpret_cast<const short8v*>(TTc + (size_t)rowl * LATENT + k);
        acc1 = __builtin_amdgcn_mfma_f32_16x16x32_bf16(ehf, tpf, acc1, 0, 0, 0);
        acc2 = __builtin_amdgcn_mfma_f32_16x16x32_bf16(elf, tpf, acc2, 0, 0, 0);
    }
    __shared__ float red[2][16][16];
#pragma unroll
    for (int r = 0; r < 4; ++r) red[wave][kgrp * 4 + r][rowl] = acc1[r] + acc2[r];
    __syncthreads();
    int nn = tid & 15;
    if (nn < 8) {
        for (int mm = tid >> 4; mm < 16; mm += 8) {
            float s2 = red[0][mm][nn] + red[0][mm][nn + 8]
                     + red[1][mm][nn] + red[1][mm][nn + 8];
            if (USE_E) s2 *= S[p * 16 + mm];
            P[((size_t)(p * 8 + si) * 16 + mm) * 8 + nn] = s2;
        }
    }
}

__global__ __launch_bounds__(256) void combine_kernel(
    const float* __restrict__ P,
    const float* __restrict__ Tcur,
    float* __restrict__ Tnxt,
    unsigned short* __restrict__ TTn,
    const float* __restrict__ Bmat,
    const float* __restrict__ xs,
    const float* __restrict__ ts,
    const float* __restrict__ mread,
    float* __restrict__ mwrite,
    float* __restrict__ ys,
    int s, int do_matvec, int do_mlp)
{
    int tid = threadIdx.x;
    if ((int)blockIdx.x < 199) {
        if (!do_matvec) return;
        __shared__ float u[17][8];
        if (tid < 136) {
            int b = tid & 7;
            int j = tid >> 3;
            float tc = ts[b * TSTEPS + s];
            float tp = (s == 0) ? -ts[b * TSTEPS + 1] : ts[b * TSTEPS + s - 1];
            float val;
            if (j == 0) val = tc - tp;
            else {
                int d = j - 1;
                float xp = (s < 2) ? xs[(b * TSTEPS) * NDATA + d] : mread[b * NDATA + d];
                val = xs[(b * TSTEPS + s) * NDATA + d] - xp;
            }
            u[j][b] = val;
        }
        __syncthreads();
        int idx = blockIdx.x * 256 + tid;
        int r = idx >> 3;
        int n = idx & 7;
        int pp = r >> 4, mm = r & 15;
        const float* Pb = P + ((size_t)pp * 8) * 128 + mm * 8 + n;
        float sum = 0.f;
#pragma unroll
        for (int si = 0; si < KSPLIT; ++si) sum += Pb[si * 128];
        float val = Tcur[r * 8 + n] + sum;
        const float* Brow = Bmat + r * 17;
#pragma unroll
        for (int j = 0; j < 17; ++j) val += Brow[j] * u[j][n];
        Tnxt[r * 8 + n] = val;
        unsigned short hb = f2bf(val);
        TTn[n * LATENT + r] = hb;
        TTn[(n + 8) * LATENT + r] = f2bf(val - bf2f(hb));
    } else {
        if (!do_mlp) return;
        int w = tid >> 6, lane = tid & 63;
        for (int it = 0; it < 2; ++it)
            mlp_batch(Tcur, ts, mwrite, ys, s - 1, w * 2 + it, lane);
    }
}

extern "C" void kernel_launch(void* const* d_in, const int* in_sizes, int n_in,
                              void* d_out, int out_size, void* d_ws, size_t ws_size,
                              hipStream_t stream) {
    const float* xs  = (const float*)d_in[0];
    const float* ts  = (const float*)d_in[1];
    const float* A   = (const float*)d_in[2];
    const float* Bm  = (const float*)d_in[3];
    const float* th0 = (const float*)d_in[4];
    float* ys = (float*)d_out;

    char* ws = (char*)d_ws;
    size_t off = 0;
    auto alloc = [&](size_t bytes) {
        void* p = ws + off;
        off += (bytes + 255) & ~(size_t)255;
        return p;
    };
    float* T0 = (float*)alloc((size_t)LATENT * 8 * sizeof(float));
    float* T1 = (float*)alloc((size_t)LATENT * 8 * sizeof(float));
    unsigned short* TTA = (unsigned short*)alloc((size_t)16 * LATENT * 2);
    unsigned short* TTB = (unsigned short*)alloc((size_t)16 * LATENT * 2);
    float* mb = (float*)alloc(2 * 8 * 16 * sizeof(float));
    float* P  = (float*)alloc((size_t)NTILE * 128 * sizeof(float));
    float* S  = (float*)alloc((size_t)LATENT * sizeof(float));
    unsigned* bar = (unsigned*)alloc(8192);
    unsigned* grpCnt   = bar;             // 16 lines x 128B
    unsigned* superCnt = bar + 512;       // own line
    unsigned* gEpoch   = bar + 544;       // 16 lines x 128B
    size_t Ebytes = (size_t)NPANEL * NCHUNK * 512 * 2;   // int16 fragment-linear: 81 MB
    bool useE = (off + Ebytes + 512) <= ws_size;
    short* Eq = nullptr;
    if (useE) {
        Eq = (short*)alloc(Ebytes);
        row_scale<<<dim3(LATENT), dim3(64), 0, stream>>>(A, S);
        int nthr = LATENT * KBLK;         // NOT divisible by 256: ceil + guard
        convert_Eq<<<dim3((nthr + 255) / 256), dim3(256), 0, stream>>>(A, S, Eq, nthr);
    }
    init_theta<<<dim3((LATENT + 255) / 256), dim3(256), 0, stream>>>(th0, T0, TTA);

    hipError_t coop = hipErrorUnknown;
    if (useE) {
        hipMemsetAsync(bar, 0, 8192, stream);
        void* kargs[] = {
            (void*)&Eq, (void*)&S, (void*)&T0, (void*)&T1,
            (void*)&TTA, (void*)&TTB, (void*)&mb, (void*)&Bm, (void*)&xs,
            (void*)&ts, (void*)&ys, (void*)&grpCnt, (void*)&superCnt, (void*)&gEpoch };
        coop = hipLaunchCooperativeKernel((void*)persistent4,
                                          dim3(NPANEL + 1), dim3(512), kargs, 0, stream);
    }
    if (coop != hipSuccess) {
        // fallback: multi-launch path
        float* T[2] = {T0, T1};
        unsigned short* TT[2] = {TTA, TTB};
        for (int s = 0; s <= TSTEPS; ++s) {
            int cur = s & 1, nxt = cur ^ 1;
            float* mwrite = mb + (s & 1) * 128;
            float* mread  = mb + ((s & 1) ^ 1) * 128;
            int dmv = (s < TSTEPS) ? 1 : 0;
            int dml = (s >= 1) ? 1 : 0;
            if (dmv) {
                if (useE)
                    partial_kernel<true><<<dim3(NTILE), dim3(128), 0, stream>>>(
                        Eq, S, A, TT[cur], P);
                else
                    partial_kernel<false><<<dim3(NTILE), dim3(128), 0, stream>>>(
                        Eq, S, A, TT[cur], P);
            }
            combine_kernel<<<dim3(200), dim3(256), 0, stream>>>(
                P, T[cur], T[nxt], TT[nxt],
                Bm, xs, ts, mread, mwrite, ys, s, dmv, dml);
        }
    }
    (void)in_sizes; (void)n_in; (void)out_size;
}

// Round 11
// 2410.425 us; speedup vs baseline: 40.7023x; 1.3354x over previous
//
#include <hip/hip_runtime.h>
#include <hip/hip_bf16.h>
#include <cmath>

#define LATENT 6368
#define TSTEPS 64
#define NDATA 16
#define NPANEL 398   /* LATENT/16 */
#define KSPLIT 8
#define NCHUNK 199   /* LATENT/32 */
#define CPS 25       /* ceil(199/8) (fallback) */
#define NTILE (NPANEL*KSPLIT)
#define KBLK 796     /* LATENT/8 */
#define AGENT __HIP_MEMORY_SCOPE_AGENT

typedef __attribute__((ext_vector_type(8))) short short8v;
typedef __attribute__((ext_vector_type(4))) float floatx4;

__device__ __forceinline__ unsigned short f2bf(float x) {
    union { float f; unsigned u; } c; c.f = x;
    unsigned r = (c.u + 0x7FFFu + ((c.u >> 16) & 1u)) >> 16;
    return (unsigned short)r;
}
__device__ __forceinline__ float bf2f(unsigned short h) {
    union { unsigned u; float f; } c; c.u = ((unsigned)h) << 16; return c.f;
}

// ---- agent-coherent (L2-bypassing, sc1) accessors for cross-block mutable data ----
__device__ __forceinline__ unsigned long long ld64c(const void* p) {
    return __hip_atomic_load((const unsigned long long*)p, __ATOMIC_RELAXED, AGENT);
}
__device__ __forceinline__ short8v ldT16c(const unsigned short* p) {
    union { short8v v; unsigned long long q[2]; } r;
    r.q[0] = ld64c(p);
    r.q[1] = ld64c(p + 4);
    return r.v;
}
__device__ __forceinline__ float ldfc(const float* p) {
    return __hip_atomic_load(p, __ATOMIC_RELAXED, AGENT);
}
__device__ __forceinline__ void stfc(float* p, float v) {
    __hip_atomic_store(p, v, __ATOMIC_RELAXED, AGENT);
}
__device__ __forceinline__ void stu16c(unsigned short* p, unsigned short v) {
    __hip_atomic_store(p, v, __ATOMIC_RELAXED, AGENT);
}

// ---------- pass 1: per-row scale S[r] = max|E_row|/32767 ----------
__global__ __launch_bounds__(64) void row_scale(const float* __restrict__ A,
                                                float* __restrict__ S) {
    int row = blockIdx.x;
    int lane = threadIdx.x;
    const float* Ar = A + (size_t)row * LATENT;
    float m = 0.f;
    for (int i = 0; i < 25; ++i) {
        int idx = i * 256 + lane * 4;
        if (idx + 4 <= LATENT) {
            float4 v = *reinterpret_cast<const float4*>(Ar + idx);
            float a0 = v.x - (idx + 0 == row ? 1.f : 0.f);
            float a1 = v.y - (idx + 1 == row ? 1.f : 0.f);
            float a2 = v.z - (idx + 2 == row ? 1.f : 0.f);
            float a3 = v.w - (idx + 3 == row ? 1.f : 0.f);
            m = fmaxf(m, fmaxf(fmaxf(fabsf(a0), fabsf(a1)), fmaxf(fabsf(a2), fabsf(a3))));
        }
    }
#pragma unroll
    for (int o = 32; o; o >>= 1) m = fmaxf(m, __shfl_xor(m, o, 64));
    if (lane == 0) S[row] = fmaxf(m, 1e-30f) * (1.0f / 32767.0f);
}

// ---------- pass 2: quantize E to int16, fragment-linear ----------
__global__ __launch_bounds__(256) void convert_Eq(const float* __restrict__ A,
                                                  const float* __restrict__ S,
                                                  short* __restrict__ Eq,
                                                  int total) {
    int t = blockIdx.x * 256 + threadIdx.x;
    if (t >= total) return;                    // LATENT*KBLK % 256 != 0 (R7 lesson)
    int row = t / KBLK;
    int kb  = t - row * KBLK;
    const float4* src = reinterpret_cast<const float4*>(A + (size_t)row * LATENT + kb * 8);
    float4 v0 = src[0];
    float4 v1 = src[1];
    float v[8] = {v0.x, v0.y, v0.z, v0.w, v1.x, v1.y, v1.z, v1.w};
    int jd = row - kb * 8;
    if (jd >= 0 && jd < 8) v[jd] -= 1.0f;
    float inv = 1.0f / S[row];
    union { short8v s; short q[8]; } o;
#pragma unroll
    for (int j = 0; j < 8; ++j) {
        float qf = rintf(v[j] * inv);
        qf = fminf(fmaxf(qf, -32767.f), 32767.f);
        o.q[j] = (short)qf;
    }
    int p = row >> 4, rowl = row & 15, c = kb >> 2, kgrp = kb & 3;
    int lane = kgrp * 16 + rowl;
    *reinterpret_cast<short8v*>(Eq + ((size_t)(p * NCHUNK + c)) * 512 + lane * 8) = o.s;
}

// Packed theta^T: rows 0..7 = bf16hi(theta[batch]), rows 8..15 = bf16lo.
__global__ __launch_bounds__(256) void init_theta(const float* __restrict__ th0,
                                                  float* __restrict__ T0,
                                                  unsigned short* __restrict__ TTA) {
    int r = blockIdx.x * blockDim.x + threadIdx.x;
    if (r >= LATENT) return;
    float v = th0[r];
#pragma unroll
    for (int b = 0; b < 8; ++b) T0[r * 8 + b] = v;
    unsigned short hb = f2bf(v);
    unsigned short lb = f2bf(v - bf2f(hb));
#pragma unroll
    for (int n = 0; n < 8; ++n) {
        TTA[n * LATENT + r] = hb;
        TTA[(n + 8) * LATENT + r] = lb;
    }
}

// ---------- wave-local MLP (plain loads; fallback path only) ----------
__device__ void mlp_batch(const float* __restrict__ Tcur, const float* __restrict__ ts,
                          float* __restrict__ mwrite, float* __restrict__ ys,
                          int i, int b, int lane) {
    float tc = ts[b * TSTEPS + i];
    float tp = (i == 0) ? -ts[b * TSTEPS + 1] : ts[b * TSTEPS + i - 1];
    float rin = 2.f * tc - tp;
    float h0 = fmaxf(Tcur[(size_t)lane * 8 + b] * rin + Tcur[(size_t)(64 + lane) * 8 + b], 0.f);
    float h1 = Tcur[(size_t)(4224 + lane) * 8 + b];
#pragma unroll 8
    for (int k = 0; k < 64; ++k)
        h1 += Tcur[(size_t)(128 + lane * 64 + k) * 8 + b] * __shfl(h0, k, 64);
    h1 = fmaxf(h1, 0.f);
    float o = 0.f;
    if (lane < 32) o = Tcur[(size_t)(6336 + lane) * 8 + b];
#pragma unroll 8
    for (int k = 0; k < 64; ++k) {
        float hk = __shfl(h1, k, 64);
        if (lane < 32) o += Tcur[(size_t)(4288 + lane * 64 + k) * 8 + b] * hk;
    }
    if (lane < 32) {
        float z = tanhf(o);
        float res;
        if (lane < 16) { res = z; mwrite[b * NDATA + lane] = z; }
        else           { res = log1pf(expf(z)); }
        ys[(size_t)b * (TSTEPS * 32) + (size_t)i * 32 + lane] = res;
    }
}

// ---------- wave-local MLP, coherent loads (persistent path) ----------
__device__ void mlp_batch_coh(const float* __restrict__ Tcur, const float* __restrict__ ts,
                              float* __restrict__ mwrite, float* __restrict__ ys,
                              int i, int b, int lane) {
    float tc = ts[b * TSTEPS + i];
    float tp = (i == 0) ? -ts[b * TSTEPS + 1] : ts[b * TSTEPS + i - 1];
    float rin = 2.f * tc - tp;
    float h0 = fmaxf(ldfc(&Tcur[(size_t)lane * 8 + b]) * rin
                     + ldfc(&Tcur[(size_t)(64 + lane) * 8 + b]), 0.f);
    float h1 = ldfc(&Tcur[(size_t)(4224 + lane) * 8 + b]);
#pragma unroll 8
    for (int k = 0; k < 64; ++k)
        h1 += ldfc(&Tcur[(size_t)(128 + lane * 64 + k) * 8 + b]) * __shfl(h0, k, 64);
    h1 = fmaxf(h1, 0.f);
    float o = 0.f;
    if (lane < 32) o = ldfc(&Tcur[(size_t)(6336 + lane) * 8 + b]);
#pragma unroll 8
    for (int k = 0; k < 64; ++k) {
        float hk = __shfl(h1, k, 64);
        if (lane < 32) o += ldfc(&Tcur[(size_t)(4288 + lane * 64 + k) * 8 + b]) * hk;
    }
    if (lane < 32) {
        float z = tanhf(o);
        float res;
        if (lane < 16) { res = z; stfc(&mwrite[b * NDATA + lane], z); }
        else           { res = log1pf(expf(z)); }
        ys[(size_t)b * (TSTEPS * 32) + (size_t)i * 32 + lane] = res;
    }
}

// ---------- grid barrier v4: FENCE-FREE (explicit vmcnt drain + relaxed counters).
// All cross-block mutable data uses sc1 (L2-bypass) accessors, so no cache
// maintenance is needed anywhere. 200 blocks, 16 groups: g<8 -> 13 blocks, else 12.
__device__ __forceinline__ void gsync2(unsigned* grpCnt, unsigned* superCnt,
                                       unsigned* gEpoch, unsigned iter) {
    asm volatile("s_waitcnt vmcnt(0)" ::: "memory");   // drain this thread's sc1 stores
    __syncthreads();                                   // (compiler also drains per-wave)
    if (threadIdx.x == 0) {
        unsigned g = blockIdx.x & 15u;
        unsigned gsz = (g < 8u) ? 13u : 12u;
        unsigned v = __hip_atomic_fetch_add(&grpCnt[g * 32], 1u, __ATOMIC_RELAXED, AGENT);
        if (v == iter * gsz - 1u) {
            unsigned w = __hip_atomic_fetch_add(superCnt, 1u, __ATOMIC_RELAXED, AGENT);
            if (w == iter * 16u - 1u) {
#pragma unroll
                for (int i2 = 0; i2 < 16; ++i2)
                    __hip_atomic_store(&gEpoch[i2 * 32], iter, __ATOMIC_RELAXED, AGENT);
            }
        }
        while (__hip_atomic_load(&gEpoch[g * 32], __ATOMIC_RELAXED, AGENT) < iter)
            __builtin_amdgcn_s_sleep(4);
    }
    __syncthreads();
}

// exact int16 -> bf16(hi8)*256 + bf16(lo8) expansion + 2 MFMAs
#define COMP(EV, TP) do {                                                       \
    union { short8v sv; unsigned short us[8]; } EHu, ELu;                       \
    _Pragma("unroll")                                                           \
    for (int j = 0; j < 8; ++j) {                                               \
        int q = (EV)[j];                                                        \
        union { float f; unsigned u; } ch, cl;                                  \
        ch.f = (float)(q >> 8);                                                 \
        cl.f = (float)(q & 255);                                                \
        EHu.us[j] = (unsigned short)(ch.u >> 16);                               \
        ELu.us[j] = (unsigned short)(cl.u >> 16);                               \
    }                                                                           \
    acc1 = __builtin_amdgcn_mfma_f32_16x16x32_bf16(EHu.sv, (TP), acc1, 0, 0, 0);\
    acc2 = __builtin_amdgcn_mfma_f32_16x16x32_bf16(ELu.sv, (TP), acc2, 0, 0, 0);\
} while (0)

#define LDE(P)  (*reinterpret_cast<const short8v*>(P))

// ---------- persistent cooperative kernel v5: 199 x 2-panel blocks + 1 MLP block,
// ---------- fence-free barrier, L2 retains Eq across steps, theta via sc1 loads ----
__global__ __launch_bounds__(1024, 4) void persistent5(
    const short* __restrict__ Eq, const float* __restrict__ S,
    float* __restrict__ T0buf, float* __restrict__ T1buf,
    unsigned short* __restrict__ TTA, unsigned short* __restrict__ TTB,
    float* __restrict__ mb,
    const float* __restrict__ Bmat, const float* __restrict__ xs,
    const float* __restrict__ ts, float* __restrict__ ys,
    unsigned* grpCnt, unsigned* superCnt, unsigned* gEpoch)
{
    __shared__ float red[16][16][16];
    __shared__ float ush[17][8];
    int tid = threadIdx.x, blk = blockIdx.x;
    int wave = tid >> 6, lane = tid & 63;
    int rowl = lane & 15, kgrp = lane >> 4;
    int panel = blk * 2 + (wave >> 3);        // blk<199: waves 0-7 -> panel 2b, 8-15 -> 2b+1
    int w8 = wave & 7;
    int cs = w8 * 25;
    int ce = (w8 < 7) ? cs + 25 : NCHUNK;     // last wave: 24 chunks
    unsigned iter = 0;
    for (int s = 0; s < TSTEPS; ++s) {
        const float* Tc = (s & 1) ? T1buf : T0buf;
        float* Tn       = (s & 1) ? T0buf : T1buf;
        const unsigned short* TTc = (s & 1) ? TTB : TTA;
        unsigned short* TTn       = (s & 1) ? TTA : TTB;
        float* mwrite = mb + (s & 1) * 128;
        const float* mread = mb + ((s & 1) ^ 1) * 128;
        if (blk < 199) {
            if (tid < 136) {
                int b = tid & 7, j = tid >> 3;
                float tc = ts[b * TSTEPS + s];
                float tp = (s == 0) ? -ts[b * TSTEPS + 1] : ts[b * TSTEPS + s - 1];
                float val;
                if (j == 0) val = tc - tp;
                else {
                    int d = j - 1;
                    float xp = (s < 2) ? xs[(b * TSTEPS) * NDATA + d]
                                       : ldfc(&mread[b * NDATA + d]);
                    val = xs[(b * TSTEPS + s) * NDATA + d] - xp;
                }
                ush[j][b] = val;
            }
            // depth-4 pipelined matvec; Eq cached (immutable), theta via sc1
            floatx4 acc1 = {0.f, 0.f, 0.f, 0.f};
            floatx4 acc2 = {0.f, 0.f, 0.f, 0.f};
            const short* ep = Eq + ((size_t)(panel * NCHUNK + cs)) * 512 + lane * 8;
            const unsigned short* tq = TTc + (size_t)rowl * LATENT + kgrp * 8 + (size_t)cs * 32;
            short8v e0 = LDE(ep),        e1 = LDE(ep + 512),
                    e2 = LDE(ep + 1024), e3 = LDE(ep + 1536);
            short8v t0 = ldT16c(tq),      t1 = ldT16c(tq + 32),
                    t2 = ldT16c(tq + 64), t3 = ldT16c(tq + 96);
            int c = cs;
            for (; c + 8 <= ce; c += 4) {
                COMP(e0, t0); e0 = LDE(ep + 2048); t0 = ldT16c(tq + 128);
                COMP(e1, t1); e1 = LDE(ep + 2560); t1 = ldT16c(tq + 160);
                COMP(e2, t2); e2 = LDE(ep + 3072); t2 = ldT16c(tq + 192);
                COMP(e3, t3); e3 = LDE(ep + 3584); t3 = ldT16c(tq + 224);
                ep += 2048; tq += 128;
            }
            COMP(e0, t0); COMP(e1, t1); COMP(e2, t2); COMP(e3, t3);
            for (int k2 = 4; c + k2 < ce; ++k2) {
                e0 = LDE(ep + k2 * 512); t0 = ldT16c(tq + k2 * 32);
                COMP(e0, t0);
            }
#pragma unroll
            for (int r = 0; r < 4; ++r)
                red[wave][kgrp * 4 + r][rowl] = 256.f * acc1[r] + acc2[r];
            __syncthreads();
            if (tid < 256) {
                int m32 = tid >> 3, n = tid & 7;
                int ph = m32 >> 4, m = m32 & 15;
                float sum = 0.f;
#pragma unroll
                for (int w = 0; w < 8; ++w)
                    sum += red[ph * 8 + w][m][n] + red[ph * 8 + w][m][n + 8];
                int r = blk * 32 + m32;
                float val = ldfc(&Tc[r * 8 + n]) + S[r] * sum;
                const float* Brow = Bmat + r * 17;
#pragma unroll
                for (int j = 0; j < 17; ++j) val += Brow[j] * ush[j][n];
                stfc(&Tn[r * 8 + n], val);
                unsigned short hb = f2bf(val);
                stu16c(&TTn[n * LATENT + r], hb);
                stu16c(&TTn[(n + 8) * LATENT + r], f2bf(val - bf2f(hb)));
            }
        } else {
            if (s >= 1 && wave < 8)
                mlp_batch_coh(Tc, ts, mwrite, ys, s - 1, wave, lane);
        }
        ++iter; gsync2(grpCnt, superCnt, gEpoch, iter);
    }
    if (blk == 199 && wave < 8)
        mlp_batch_coh(T0buf, ts, mb, ys, TSTEPS - 1, wave, lane);
}

// ---------- fallback path (multi-launch, int16 E) ----------
template<bool USE_E>
__global__ __launch_bounds__(128) void partial_kernel(
    const short* __restrict__ Eq, const float* __restrict__ S,
    const float* __restrict__ Af,
    const unsigned short* __restrict__ TTc,
    float* __restrict__ P)
{
    int blk = blockIdx.x;
    int p  = blk >> 3;
    int si = blk & 7;
    int tid = threadIdx.x;
    int wave = tid >> 6;
    int lane = tid & 63;
    int rowl = lane & 15;
    int kgrp = lane >> 4;
    int row = p * 16 + rowl;
    int c0 = si * CPS;
    int c1 = c0 + CPS; if (c1 > NCHUNK) c1 = NCHUNK;
    int nch = c1 - c0;
    int half = (nch + 1) >> 1;
    int csw = c0 + wave * half;
    int cew = csw + half; if (cew > c1) cew = c1;
    floatx4 acc1 = {0.f, 0.f, 0.f, 0.f};
    floatx4 acc2 = {0.f, 0.f, 0.f, 0.f};
    for (int c = csw; c < cew; ++c) {
        int k = c * 32 + kgrp * 8;
        short8v ehf, elf;
        if (USE_E) {
            short8v ev = *reinterpret_cast<const short8v*>(
                Eq + ((size_t)(p * NCHUNK + c)) * 512 + lane * 8);
            union { short8v sv; unsigned short us[8]; } EH, EL;
#pragma unroll
            for (int j = 0; j < 8; ++j) {
                int q = ev[j];
                union { float f; unsigned u; } ch2, cl2;
                ch2.f = (float)(q >> 8);
                cl2.f = (float)(q & 255);
                EH.us[j] = (unsigned short)(ch2.u >> 16);
                EL.us[j] = (unsigned short)(cl2.u >> 16);
            }
            ehf = EH.sv; elf = EL.sv;
        } else {
            const float* ap = Af + (size_t)row * LATENT + k;
            float v[8];
#pragma unroll
            for (int j = 0; j < 8; ++j) v[j] = ap[j];
            int jd = row - k;
            if (jd >= 0 && jd < 8) v[jd] -= 1.0f;
            union { short8v sv; unsigned short us[8]; } ch, cl;
#pragma unroll
            for (int j = 0; j < 8; ++j) {
                unsigned short hb = f2bf(v[j]);
                ch.us[j] = hb;
                cl.us[j] = f2bf(v[j] - bf2f(hb));
            }
            ehf = ch.sv; elf = cl.sv;
        }
        short8v tpf = *reinterpret_cast<const short8v*>(TTc + (size_t)rowl * LATENT + k);
        acc1 = __builtin_amdgcn_mfma_f32_16x16x32_bf16(ehf, tpf, acc1, 0, 0, 0);
        acc2 = __builtin_amdgcn_mfma_f32_16x16x32_bf16(elf, tpf, acc2, 0, 0, 0);
    }
    __shared__ float red[2][16][16];
#pragma unroll
    for (int r = 0; r < 4; ++r)
        red[wave][kgrp * 4 + r][rowl] = USE_E ? (256.f * acc1[r] + acc2[r])
                                              : (acc1[r] + acc2[r]);
    __syncthreads();
    int nn = tid & 15;
    if (nn < 8) {
        for (int mm = tid >> 4; mm < 16; mm += 8) {
            float s2 = red[0][mm][nn] + red[0][mm][nn + 8]
                     + red[1][mm][nn] + red[1][mm][nn + 8];
            if (USE_E) s2 *= S[p * 16 + mm];
            P[((size_t)(p * 8 + si) * 16 + mm) * 8 + nn] = s2;
        }
    }
}

__global__ __launch_bounds__(256) void combine_kernel(
    const float* __restrict__ P,
    const float* __restrict__ Tcur,
    float* __restrict__ Tnxt,
    unsigned short* __restrict__ TTn,
    const float* __restrict__ Bmat,
    const float* __restrict__ xs,
    const float* __restrict__ ts,
    const float* __restrict__ mread,
    float* __restrict__ mwrite,
    float* __restrict__ ys,
    int s, int do_matvec, int do_mlp)
{
    int tid = threadIdx.x;
    if ((int)blockIdx.x < 199) {
        if (!do_matvec) return;
        __shared__ float u[17][8];
        if (tid < 136) {
            int b = tid & 7;
            int j = tid >> 3;
            float tc = ts[b * TSTEPS + s];
            float tp = (s == 0) ? -ts[b * TSTEPS + 1] : ts[b * TSTEPS + s - 1];
            float val;
            if (j == 0) val = tc - tp;
            else {
                int d = j - 1;
                float xp = (s < 2) ? xs[(b * TSTEPS) * NDATA + d] : mread[b * NDATA + d];
                val = xs[(b * TSTEPS + s) * NDATA + d] - xp;
            }
            u[j][b] = val;
        }
        __syncthreads();
        int idx = blockIdx.x * 256 + tid;
        int r = idx >> 3;
        int n = idx & 7;
        int pp = r >> 4, mm = r & 15;
        const float* Pb = P + ((size_t)pp * 8) * 128 + mm * 8 + n;
        float sum = 0.f;
#pragma unroll
        for (int si = 0; si < KSPLIT; ++si) sum += Pb[si * 128];
        float val = Tcur[r * 8 + n] + sum;
        const float* Brow = Bmat + r * 17;
#pragma unroll
        for (int j = 0; j < 17; ++j) val += Brow[j] * u[j][n];
        Tnxt[r * 8 + n] = val;
        unsigned short hb = f2bf(val);
        TTn[n * LATENT + r] = hb;
        TTn[(n + 8) * LATENT + r] = f2bf(val - bf2f(hb));
    } else {
        if (!do_mlp) return;
        int w = tid >> 6, lane = tid & 63;
        for (int it = 0; it < 2; ++it)
            mlp_batch(Tcur, ts, mwrite, ys, s - 1, w * 2 + it, lane);
    }
}

extern "C" void kernel_launch(void* const* d_in, const int* in_sizes, int n_in,
                              void* d_out, int out_size, void* d_ws, size_t ws_size,
                              hipStream_t stream) {
    const float* xs  = (const float*)d_in[0];
    const float* ts  = (const float*)d_in[1];
    const float* A   = (const float*)d_in[2];
    const float* Bm  = (const float*)d_in[3];
    const float* th0 = (const float*)d_in[4];
    float* ys = (float*)d_out;

    char* ws = (char*)d_ws;
    size_t off = 0;
    auto alloc = [&](size_t bytes) {
        void* p = ws + off;
        off += (bytes + 255) & ~(size_t)255;
        return p;
    };
    float* T0 = (float*)alloc((size_t)LATENT * 8 * sizeof(float));
    float* T1 = (float*)alloc((size_t)LATENT * 8 * sizeof(float));
    unsigned short* TTA = (unsigned short*)alloc((size_t)16 * LATENT * 2);
    unsigned short* TTB = (unsigned short*)alloc((size_t)16 * LATENT * 2);
    float* mb = (float*)alloc(2 * 8 * 16 * sizeof(float));
    float* P  = (float*)alloc((size_t)NTILE * 128 * sizeof(float));
    float* S  = (float*)alloc((size_t)LATENT * sizeof(float));
    unsigned* bar = (unsigned*)alloc(8192);
    unsigned* grpCnt   = bar;             // 16 lines x 128B
    unsigned* superCnt = bar + 512;       // own line
    unsigned* gEpoch   = bar + 544;       // 16 lines x 128B
    size_t Ebytes = (size_t)NPANEL * NCHUNK * 512 * 2;   // int16 fragment-linear: 81 MB
    bool useE = (off + Ebytes + 512) <= ws_size;
    short* Eq = nullptr;
    if (useE) {
        Eq = (short*)alloc(Ebytes);
        row_scale<<<dim3(LATENT), dim3(64), 0, stream>>>(A, S);
        int nthr = LATENT * KBLK;         // NOT divisible by 256: ceil + guard
        convert_Eq<<<dim3((nthr + 255) / 256), dim3(256), 0, stream>>>(A, S, Eq, nthr);
    }
    init_theta<<<dim3((LATENT + 255) / 256), dim3(256), 0, stream>>>(th0, T0, TTA);

    hipError_t coop = hipErrorUnknown;
    if (useE) {
        hipMemsetAsync(bar, 0, 8192, stream);
        void* kargs[] = {
            (void*)&Eq, (void*)&S, (void*)&T0, (void*)&T1,
            (void*)&TTA, (void*)&TTB, (void*)&mb, (void*)&Bm, (void*)&xs,
            (void*)&ts, (void*)&ys, (void*)&grpCnt, (void*)&superCnt, (void*)&gEpoch };
        coop = hipLaunchCooperativeKernel((void*)persistent5,
                                          dim3(200), dim3(1024), kargs, 0, stream);
    }
    if (coop != hipSuccess) {
        // fallback: multi-launch path
        float* T[2] = {T0, T1};
        unsigned short* TT[2] = {TTA, TTB};
        for (int s = 0; s <= TSTEPS; ++s) {
            int cur = s & 1, nxt = cur ^ 1;
            float* mwrite = mb + (s & 1) * 128;
            float* mread  = mb + ((s & 1) ^ 1) * 128;
            int dmv = (s < TSTEPS) ? 1 : 0;
            int dml = (s >= 1) ? 1 : 0;
            if (dmv) {
                if (useE)
                    partial_kernel<true><<<dim3(NTILE), dim3(128), 0, stream>>>(
                        Eq, S, A, TT[cur], P);
                else
                    partial_kernel<false><<<dim3(NTILE), dim3(128), 0, stream>>>(
                        Eq, S, A, TT[cur], P);
            }
            combine_kernel<<<dim3(200), dim3(256), 0, stream>>>(
                P, T[cur], T[nxt], TT[nxt],
                Bm, xs, ts, mread, mwrite, ys, s, dmv, dml);
        }
    }
    (void)in_sizes; (void)n_in; (void)out_size;
}